// Round 2
// baseline (1359.465 us; speedup 1.0000x reference)
//
#include <hip/hip_runtime.h>

// Conformer block, fp32. B=4, T=2048, D=256, H=8, HD=32, K=31.
#define Bn 4
#define Tn 2048
#define Dn 256
#define Hn 8
#define HDn 32
#define KW 31
#define EPSV 1e-5f
#define NTOK (Bn * Tn)   // 8192 tokens

__device__ __forceinline__ float sigmoidf_(float x) { return 1.f / (1.f + __expf(-x)); }
__device__ __forceinline__ float rlane(float v, int l) {
    return __uint_as_float((unsigned)__builtin_amdgcn_readlane(__float_as_uint(v), l));
}

// ---------------- LayerNorm: one wave per row (D=256 -> 4 floats/lane) ----------------
__global__ __launch_bounds__(256) void ln_kernel(const float* __restrict__ x,
                                                 const float* __restrict__ g,
                                                 const float* __restrict__ b,
                                                 float* __restrict__ y)
{
    const int row  = blockIdx.x * 4 + (threadIdx.x >> 6);
    const int lane = threadIdx.x & 63;
    const float* xr = x + (size_t)row * Dn + lane * 4;
    float4 v = *(const float4*)xr;
    float s = v.x + v.y + v.z + v.w;
#pragma unroll
    for (int o = 32; o > 0; o >>= 1) s += __shfl_xor(s, o, 64);
    const float mu = s * (1.f / Dn);
    const float dx = v.x - mu, dy = v.y - mu, dz = v.z - mu, dw = v.w - mu;
    float ss = dx * dx + dy * dy + dz * dz + dw * dw;
#pragma unroll
    for (int o = 32; o > 0; o >>= 1) ss += __shfl_xor(ss, o, 64);
    const float rstd = rsqrtf(ss * (1.f / Dn) + EPSV);
    const float4 gv = *(const float4*)(g + lane * 4);
    const float4 bv = *(const float4*)(b + lane * 4);
    float4 o4;
    o4.x = dx * rstd * gv.x + bv.x;
    o4.y = dy * rstd * gv.y + bv.y;
    o4.z = dz * rstd * gv.z + bv.z;
    o4.w = dw * rstd * gv.w + bv.w;
    *(float4*)(y + (size_t)row * Dn + lane * 4) = o4;
}

// ============ GEMM BIG: 128x128 tile, 8x8 microtile, reg-prefetch. For N in {512,768} ============
// EPI: 0 = +bias ; 1 = silu(+bias)
#define GBK 16

template <int EPI>
__global__ __launch_bounds__(256) void gemm_big_kernel(const float* __restrict__ A,
                                                       const float* __restrict__ Bw,
                                                       const float* __restrict__ bias,
                                                       float* __restrict__ C,
                                                       int M, int N, int K)
{
    __shared__ float As[GBK][132];   // transposed: As[k][m]
    __shared__ float Bs[GBK][132];
    const int tid  = threadIdx.x;
    const int tx   = tid & 15;          // col group: cols tx*8 .. tx*8+7
    const int ty   = tid >> 4;          // row group: rows ty*8 .. ty*8+7
    const int row0 = blockIdx.x * 128;
    const int col0 = blockIdx.y * 128;
    const int arow = tid >> 1;          // 0..127
    const int acol = (tid & 1) * 8;     // 0 or 8
    const int br   = tid >> 5;          // 0..7 (k-rows br and br+8)
    const int bc   = (tid & 31) * 4;    // 0..124
    const float* Ag = A + (size_t)(row0 + arow) * K + acol;
    const float* Bg = Bw + (size_t)br * N + col0 + bc;

    float4 pa0 = *(const float4*)(Ag);
    float4 pa1 = *(const float4*)(Ag + 4);
    float4 pb0 = *(const float4*)(Bg);
    float4 pb1 = *(const float4*)(Bg + (size_t)8 * N);

    float acc[8][8];
#pragma unroll
    for (int i = 0; i < 8; ++i)
#pragma unroll
        for (int j = 0; j < 8; ++j) acc[i][j] = 0.f;

    for (int k0 = 0; k0 < K; k0 += GBK) {
        As[acol + 0][arow] = pa0.x;
        As[acol + 1][arow] = pa0.y;
        As[acol + 2][arow] = pa0.z;
        As[acol + 3][arow] = pa0.w;
        As[acol + 4][arow] = pa1.x;
        As[acol + 5][arow] = pa1.y;
        As[acol + 6][arow] = pa1.z;
        As[acol + 7][arow] = pa1.w;
        *(float4*)&Bs[br][bc]     = pb0;
        *(float4*)&Bs[br + 8][bc] = pb1;
        __syncthreads();
        if (k0 + GBK < K) {   // prefetch next tiles into regs; latency hides under kk-loop
            pa0 = *(const float4*)(Ag + k0 + GBK);
            pa1 = *(const float4*)(Ag + k0 + GBK + 4);
            pb0 = *(const float4*)(Bg + (size_t)(k0 + GBK) * N);
            pb1 = *(const float4*)(Bg + (size_t)(k0 + GBK + 8) * N);
        }
#pragma unroll
        for (int kk = 0; kk < GBK; ++kk) {
            float av[8], bv[8];
            *(float4*)&av[0] = *(const float4*)&As[kk][ty * 8];
            *(float4*)&av[4] = *(const float4*)&As[kk][ty * 8 + 4];
            *(float4*)&bv[0] = *(const float4*)&Bs[kk][tx * 8];
            *(float4*)&bv[4] = *(const float4*)&Bs[kk][tx * 8 + 4];
#pragma unroll
            for (int i = 0; i < 8; ++i)
#pragma unroll
                for (int j = 0; j < 8; ++j) acc[i][j] = fmaf(av[i], bv[j], acc[i][j]);
        }
        __syncthreads();
    }

    const int c = col0 + tx * 8;
    const float4 bj0 = *(const float4*)(bias + c);
    const float4 bj1 = *(const float4*)(bias + c + 4);
#pragma unroll
    for (int i = 0; i < 8; ++i) {
        const int r = row0 + ty * 8 + i;
        float4 v0, v1;
        v0.x = acc[i][0] + bj0.x; v0.y = acc[i][1] + bj0.y;
        v0.z = acc[i][2] + bj0.z; v0.w = acc[i][3] + bj0.w;
        v1.x = acc[i][4] + bj1.x; v1.y = acc[i][5] + bj1.y;
        v1.z = acc[i][6] + bj1.z; v1.w = acc[i][7] + bj1.w;
        if (EPI == 1) {
            v0.x *= sigmoidf_(v0.x); v0.y *= sigmoidf_(v0.y);
            v0.z *= sigmoidf_(v0.z); v0.w *= sigmoidf_(v0.w);
            v1.x *= sigmoidf_(v1.x); v1.y *= sigmoidf_(v1.y);
            v1.z *= sigmoidf_(v1.z); v1.w *= sigmoidf_(v1.w);
        }
        *(float4*)(C + (size_t)r * N + c)     = v0;
        *(float4*)(C + (size_t)r * N + c + 4) = v1;
    }
}

// ============ GEMM SMALL: 128x64 tile, 8x4 microtile, reg-prefetch. For N=256 ============
// EPI: 0 = +bias ; 2 = res + scale*(+bias)
template <int EPI>
__global__ __launch_bounds__(256) void gemm_small_kernel(const float* __restrict__ A,
                                                         const float* __restrict__ Bw,
                                                         const float* __restrict__ bias,
                                                         const float* __restrict__ res,
                                                         float* __restrict__ C,
                                                         int M, int N, int K, float scale)
{
    __shared__ float As[GBK][132];
    __shared__ float Bs[GBK][68];
    const int tid  = threadIdx.x;
    const int tx   = tid & 15;          // cols tx*4 .. tx*4+3 (contiguous -> float4)
    const int ty   = tid >> 4;          // rows ty*8 .. ty*8+7
    const int row0 = blockIdx.x * 128;
    const int col0 = blockIdx.y * 64;
    const int arow = tid >> 1;
    const int acol = (tid & 1) * 8;
    const int brow = tid >> 4;          // 0..15
    const int bcol = (tid & 15) * 4;    // 0..60
    const float* Ag = A + (size_t)(row0 + arow) * K + acol;
    const float* Bg = Bw + (size_t)brow * N + col0 + bcol;

    float4 pa0 = *(const float4*)(Ag);
    float4 pa1 = *(const float4*)(Ag + 4);
    float4 pb0 = *(const float4*)(Bg);

    float acc[8][4];
#pragma unroll
    for (int i = 0; i < 8; ++i)
#pragma unroll
        for (int j = 0; j < 4; ++j) acc[i][j] = 0.f;

    for (int k0 = 0; k0 < K; k0 += GBK) {
        As[acol + 0][arow] = pa0.x;
        As[acol + 1][arow] = pa0.y;
        As[acol + 2][arow] = pa0.z;
        As[acol + 3][arow] = pa0.w;
        As[acol + 4][arow] = pa1.x;
        As[acol + 5][arow] = pa1.y;
        As[acol + 6][arow] = pa1.z;
        As[acol + 7][arow] = pa1.w;
        *(float4*)&Bs[brow][bcol] = pb0;
        __syncthreads();
        if (k0 + GBK < K) {
            pa0 = *(const float4*)(Ag + k0 + GBK);
            pa1 = *(const float4*)(Ag + k0 + GBK + 4);
            pb0 = *(const float4*)(Bg + (size_t)(k0 + GBK) * N);
        }
#pragma unroll
        for (int kk = 0; kk < GBK; ++kk) {
            float av[8], bv[4];
            *(float4*)&av[0] = *(const float4*)&As[kk][ty * 8];
            *(float4*)&av[4] = *(const float4*)&As[kk][ty * 8 + 4];
            *(float4*)&bv[0] = *(const float4*)&Bs[kk][tx * 4];
#pragma unroll
            for (int i = 0; i < 8; ++i)
#pragma unroll
                for (int j = 0; j < 4; ++j) acc[i][j] = fmaf(av[i], bv[j], acc[i][j]);
        }
        __syncthreads();
    }

    const int c = col0 + tx * 4;
    const float4 bj = *(const float4*)(bias + c);
#pragma unroll
    for (int i = 0; i < 8; ++i) {
        const int r = row0 + ty * 8 + i;
        float4 v;
        v.x = acc[i][0] + bj.x; v.y = acc[i][1] + bj.y;
        v.z = acc[i][2] + bj.z; v.w = acc[i][3] + bj.w;
        if (EPI == 2) {
            const float4 rv = *(const float4*)(res + (size_t)r * N + c);
            v.x = rv.x + scale * v.x; v.y = rv.y + scale * v.y;
            v.z = rv.z + scale * v.z; v.w = rv.w + scale * v.w;
        }
        *(float4*)(C + (size_t)r * N + c) = v;
    }
}

// ---------------- Attention: K/V rows in registers, readlane broadcast ----------------
// qkv: [B,T,768] (Q 0..255, K 256..511, V 512..767; within each: h*32+d)
// Lane l of each wave owns K/V row (t0+l); row j broadcast to all lanes via v_readlane
// (j wave-uniform -> SGPR operand feeds v_fmac directly; zero LDS in inner loop).
__global__ __launch_bounds__(256) void attn_kernel(const float* __restrict__ qkv,
                                                   float* __restrict__ out)
{
    const int bh   = blockIdx.y;
    const int b    = bh >> 3;
    const int h    = bh & 7;
    const int qr   = blockIdx.x * 256 + threadIdx.x;
    const int lane = threadIdx.x & 63;
    __shared__ float Ks[64][36];   // +4 pad: reg-load row reads land on distinct bank groups
    __shared__ float Vs[64][36];
    const float* base = qkv + (size_t)b * Tn * 768;

    float q[32];
    const float* qp = base + (size_t)qr * 768 + h * HDn;
#pragma unroll
    for (int i = 0; i < 8; ++i) *(float4*)&q[i * 4] = *(const float4*)(qp + i * 4);

    float m = -1e30f, l = 0.f;
    float acc[32];
#pragma unroll
    for (int d = 0; d < 32; ++d) acc[d] = 0.f;
    const float scale = 0.17677669529663687f;  // 1/sqrt(32)

    for (int t0 = 0; t0 < Tn; t0 += 64) {
        __syncthreads();
#pragma unroll
        for (int r = 0; r < 2; ++r) {
            const int i   = threadIdx.x + r * 256;   // 0..511
            const int row = i >> 3;
            const int seg = (i & 7) * 4;
            const float* kp = base + (size_t)(t0 + row) * 768 + Dn + h * HDn + seg;
            *(float4*)&Ks[row][seg] = *(const float4*)kp;
            *(float4*)&Vs[row][seg] = *(const float4*)(kp + Dn);
        }
        __syncthreads();
        float kr[32], vr[32];
#pragma unroll
        for (int d0 = 0; d0 < 8; ++d0) {
            *(float4*)&kr[d0 * 4] = *(const float4*)&Ks[lane][d0 * 4];
            *(float4*)&vr[d0 * 4] = *(const float4*)&Vs[lane][d0 * 4];
        }

        for (int j = 0; j < 64; ++j) {
            float s0 = 0.f, s1 = 0.f, s2 = 0.f, s3 = 0.f;
#pragma unroll
            for (int d = 0; d < 32; d += 4) {
                s0 = fmaf(q[d + 0], rlane(kr[d + 0], j), s0);
                s1 = fmaf(q[d + 1], rlane(kr[d + 1], j), s1);
                s2 = fmaf(q[d + 2], rlane(kr[d + 2], j), s2);
                s3 = fmaf(q[d + 3], rlane(kr[d + 3], j), s3);
            }
            const float s = ((s0 + s1) + (s2 + s3)) * scale;
            const float gap = s - m;
            if (__all(gap <= 8.f)) {        // T13 defer-max: common path, no rescale
                const float p = __expf(gap);
                l += p;
#pragma unroll
                for (int d = 0; d < 32; ++d)
                    acc[d] = fmaf(p, rlane(vr[d], j), acc[d]);
            } else {                        // rare: new max beyond threshold
                const float mn = fmaxf(m, s);
                const float f  = __expf(m - mn);
                const float p  = __expf(s - mn);
                l = l * f + p;
                m = mn;
#pragma unroll
                for (int d = 0; d < 32; ++d)
                    acc[d] = fmaf(acc[d], f, p * rlane(vr[d], j));
            }
        }
    }
    const float inv = 1.f / l;
    float* op = out + (size_t)(b * Tn + qr) * Dn + h * HDn;
#pragma unroll
    for (int d = 0; d < 32; d += 4) {
        float4 o4;
        o4.x = acc[d] * inv; o4.y = acc[d + 1] * inv;
        o4.z = acc[d + 2] * inv; o4.w = acc[d + 3] * inv;
        *(float4*)(op + d) = o4;
    }
}

// ---------------- GLU: [B,T,512] -> [B,T,256], a*sigmoid(g) ----------------
__global__ __launch_bounds__(256) void glu_kernel(const float* __restrict__ h,
                                                  float* __restrict__ outp)
{
    const size_t i   = (size_t)blockIdx.x * 256 + threadIdx.x;  // over B*T*D/4
    const size_t row = i / (Dn / 4);
    const int    c4  = (int)(i % (Dn / 4)) * 4;
    const float* hp  = h + row * (2 * Dn);
    const float4 a = *(const float4*)(hp + c4);
    const float4 g = *(const float4*)(hp + Dn + c4);
    float4 r;
    r.x = a.x * sigmoidf_(g.x);
    r.y = a.y * sigmoidf_(g.y);
    r.z = a.z * sigmoidf_(g.z);
    r.w = a.w * sigmoidf_(g.w);
    *(float4*)(outp + row * Dn + c4) = r;
}

// ---------------- Depthwise conv over time, K=31, layout [B,T,D] ----------------
__global__ __launch_bounds__(256) void dwconv_kernel(const float* __restrict__ in,
                                                     const float* __restrict__ w,
                                                     const float* __restrict__ wb,
                                                     float* __restrict__ outp)
{
    const int d  = threadIdx.x;
    const int b  = blockIdx.y;
    const int t0 = blockIdx.x * 8;
    float wr[KW];
#pragma unroll
    for (int k = 0; k < KW; ++k) wr[k] = w[d * KW + k];
    const float bias = wb[d];
    const float* bin  = in + (size_t)b * Tn * Dn + d;
    float* bout       = outp + (size_t)b * Tn * Dn + d;
    if (t0 >= (KW / 2) + 1 && t0 + 8 + KW / 2 <= Tn) {
        for (int i = 0; i < 8; ++i) {
            const int t = t0 + i;
            float s = bias;
#pragma unroll
            for (int k = 0; k < KW; ++k) s = fmaf(bin[(size_t)(t + k - KW / 2) * Dn], wr[k], s);
            bout[(size_t)t * Dn] = s;
        }
    } else {
        for (int i = 0; i < 8; ++i) {
            const int t = t0 + i;
            float s = bias;
#pragma unroll
            for (int k = 0; k < KW; ++k) {
                const int tt = t + k - KW / 2;
                if (tt >= 0 && tt < Tn) s = fmaf(bin[(size_t)tt * Dn], wr[k], s);
            }
            bout[(size_t)t * Dn] = s;
        }
    }
}

// ---------------- BatchNorm stats, 2-stage coalesced ----------------
__global__ __launch_bounds__(256) void bnpart_kernel(const float* __restrict__ in,
                                                     float* __restrict__ part)
{
    const int d  = threadIdx.x;
    const int bk = blockIdx.x;                 // 256 blocks x 32 tokens
    float s = 0.f, ss = 0.f;
    const float* p = in + (size_t)bk * 32 * Dn + d;
    for (int t = 0; t < 32; ++t) {
        const float v = p[(size_t)t * Dn];
        s += v;
        ss = fmaf(v, v, ss);
    }
    part[bk * 512 + d]       = s;
    part[bk * 512 + 256 + d] = ss;
}

__global__ __launch_bounds__(256) void bnfin_kernel(const float* __restrict__ part,
                                                    float* __restrict__ meanp,
                                                    float* __restrict__ rstdp)
{
    const int d = threadIdx.x;
    float s = 0.f, ss = 0.f;
    for (int k = 0; k < 256; ++k) {
        s  += part[k * 512 + d];
        ss += part[k * 512 + 256 + d];
    }
    const float mu  = s * (1.f / NTOK);
    const float var = ss * (1.f / NTOK) - mu * mu;
    meanp[d] = mu;
    rstdp[d] = rsqrtf(var + EPSV);
}

// ---------------- BN apply + SiLU ----------------
__global__ __launch_bounds__(256) void bnsilu_kernel(const float* __restrict__ in,
                                                     const float* __restrict__ meanp,
                                                     const float* __restrict__ rstdp,
                                                     const float* __restrict__ g,
                                                     const float* __restrict__ bb,
                                                     float* __restrict__ outp)
{
    const size_t idx = ((size_t)blockIdx.x * 256 + threadIdx.x) * 4;
    const int d = (int)(idx & (Dn - 1));
    const float4 v = *(const float4*)(in + idx);
    float4 r;
    {
        float t;
        t = (v.x - meanp[d + 0]) * rstdp[d + 0] * g[d + 0] + bb[d + 0]; r.x = t * sigmoidf_(t);
        t = (v.y - meanp[d + 1]) * rstdp[d + 1] * g[d + 1] + bb[d + 1]; r.y = t * sigmoidf_(t);
        t = (v.z - meanp[d + 2]) * rstdp[d + 2] * g[d + 2] + bb[d + 2]; r.z = t * sigmoidf_(t);
        t = (v.w - meanp[d + 3]) * rstdp[d + 3] * g[d + 3] + bb[d + 3]; r.w = t * sigmoidf_(t);
    }
    *(float4*)(outp + idx) = r;
}

// ---------------- launch ----------------
extern "C" void kernel_launch(void* const* d_in, const int* in_sizes, int n_in,
                              void* d_out, int out_size, void* d_ws, size_t ws_size,
                              hipStream_t stream)
{
    const float* x         = (const float*)d_in[0];
    const float* ff1_ln_g  = (const float*)d_in[1];
    const float* ff1_ln_b  = (const float*)d_in[2];
    const float* ff1_w1    = (const float*)d_in[3];
    const float* ff1_b1    = (const float*)d_in[4];
    const float* ff1_w2    = (const float*)d_in[5];
    const float* ff1_b2    = (const float*)d_in[6];
    const float* mhsa_ln_g = (const float*)d_in[7];
    const float* mhsa_ln_b = (const float*)d_in[8];
    const float* qkv_w     = (const float*)d_in[9];
    const float* qkv_b     = (const float*)d_in[10];
    const float* out_w     = (const float*)d_in[11];
    const float* out_b     = (const float*)d_in[12];
    const float* conv_ln_g = (const float*)d_in[13];
    const float* conv_ln_b = (const float*)d_in[14];
    const float* pw1_w     = (const float*)d_in[15];
    const float* pw1_b     = (const float*)d_in[16];
    const float* dw_w      = (const float*)d_in[17];
    const float* dw_b      = (const float*)d_in[18];
    const float* bn_g      = (const float*)d_in[19];
    const float* bn_b      = (const float*)d_in[20];
    const float* pw2_w     = (const float*)d_in[21];
    const float* pw2_b     = (const float*)d_in[22];
    const float* ff2_ln_g  = (const float*)d_in[23];
    const float* ff2_ln_b  = (const float*)d_in[24];
    const float* ff2_w1    = (const float*)d_in[25];
    const float* ff2_b1    = (const float*)d_in[26];
    const float* ff2_w2    = (const float*)d_in[27];
    const float* ff2_b2    = (const float*)d_in[28];
    const float* fin_ln_g  = (const float*)d_in[29];
    const float* fin_ln_b  = (const float*)d_in[30];

    float* ws   = (float*)d_ws;
    float* R    = ws;                 // residual stream [8192,256]
    float* Nb   = R + 2097152;        // LN output      [8192,256]
    float* HQ   = Nb + 2097152;       // FF hidden [8192,512] / QKV [8192,768] (time-shared)
    float* part = HQ + 6291456;       // BN partials [256][512]
    float* mean = part + 131072;      // [256]
    float* rstd = mean + 256;         // [256]
    float* Cb   = Nb;                 // conv output aliases Nb (Nb dead after pw1 gemm)
    float* Ab   = (float*)d_out;      // [8192,256] scratch (attn/GLU/BN out), final output

    const dim3 blk(256);

    // ---- FF1 ----
    ln_kernel<<<NTOK / 4, blk, 0, stream>>>(x, ff1_ln_g, ff1_ln_b, Nb);
    gemm_big_kernel<1><<<dim3(64, 4), blk, 0, stream>>>(Nb, ff1_w1, ff1_b1, HQ, NTOK, 512, 256);
    gemm_small_kernel<2><<<dim3(64, 4), blk, 0, stream>>>(HQ, ff1_w2, ff1_b2, x, R, NTOK, 256, 512, 0.5f);

    // ---- MHSA ----
    ln_kernel<<<NTOK / 4, blk, 0, stream>>>(R, mhsa_ln_g, mhsa_ln_b, Nb);
    gemm_big_kernel<0><<<dim3(64, 6), blk, 0, stream>>>(Nb, qkv_w, qkv_b, HQ, NTOK, 768, 256);
    attn_kernel<<<dim3(8, 32), blk, 0, stream>>>(HQ, Ab);
    gemm_small_kernel<2><<<dim3(64, 4), blk, 0, stream>>>(Ab, out_w, out_b, R, R, NTOK, 256, 256, 1.f);

    // ---- Conv module ----
    ln_kernel<<<NTOK / 4, blk, 0, stream>>>(R, conv_ln_g, conv_ln_b, Nb);
    gemm_big_kernel<0><<<dim3(64, 4), blk, 0, stream>>>(Nb, pw1_w, pw1_b, HQ, NTOK, 512, 256);
    glu_kernel<<<NTOK * Dn / 4 / 256, blk, 0, stream>>>(HQ, Ab);
    dwconv_kernel<<<dim3(Tn / 8, Bn), blk, 0, stream>>>(Ab, dw_w, dw_b, Cb);
    bnpart_kernel<<<256, blk, 0, stream>>>(Cb, part);
    bnfin_kernel<<<1, blk, 0, stream>>>(part, mean, rstd);
    bnsilu_kernel<<<NTOK * Dn / 4 / 256, blk, 0, stream>>>(Cb, mean, rstd, bn_g, bn_b, Ab);
    gemm_small_kernel<2><<<dim3(64, 4), blk, 0, stream>>>(Ab, pw2_w, pw2_b, R, R, NTOK, 256, 256, 1.f);

    // ---- FF2 ----
    ln_kernel<<<NTOK / 4, blk, 0, stream>>>(R, ff2_ln_g, ff2_ln_b, Nb);
    gemm_big_kernel<1><<<dim3(64, 4), blk, 0, stream>>>(Nb, ff2_w1, ff2_b1, HQ, NTOK, 512, 256);
    gemm_small_kernel<2><<<dim3(64, 4), blk, 0, stream>>>(HQ, ff2_w2, ff2_b2, R, R, NTOK, 256, 512, 0.5f);

    // ---- Final LN ----
    ln_kernel<<<NTOK / 4, blk, 0, stream>>>(R, fin_ln_g, fin_ln_b, (float*)d_out);
}

// Round 3
// 562.182 us; speedup vs baseline: 2.4182x; 2.4182x over previous
//
#include <hip/hip_runtime.h>
#include <hip/hip_bf16.h>

// Conformer block. B=4, T=2048, D=256, H=8, HD=32, K=31.
// Attention: bf16 MFMA (16x16x32). GEMMs/LN/conv: fp32 (convert next round if absmax allows).
#define Bn 4
#define Tn 2048
#define Dn 256
#define Hn 8
#define HDn 32
#define KW 31
#define EPSV 1e-5f
#define NTOK (Bn * Tn)   // 8192 tokens

typedef __attribute__((ext_vector_type(8))) short bf16x8;   // 8 bf16 = 4 VGPR (MFMA A/B frag)
typedef __attribute__((ext_vector_type(4))) float f32x4;    // MFMA C/D frag

__device__ __forceinline__ float sigmoidf_(float x) { return 1.f / (1.f + __expf(-x)); }
__device__ __forceinline__ unsigned short f2bfu(float f) {
    __hip_bfloat16 h = __float2bfloat16(f);
    unsigned short u; __builtin_memcpy(&u, &h, 2); return u;
}

// ---------------- LayerNorm: one wave per row (D=256 -> 4 floats/lane) ----------------
__global__ __launch_bounds__(256) void ln_kernel(const float* __restrict__ x,
                                                 const float* __restrict__ g,
                                                 const float* __restrict__ b,
                                                 float* __restrict__ y)
{
    const int row  = blockIdx.x * 4 + (threadIdx.x >> 6);
    const int lane = threadIdx.x & 63;
    const float* xr = x + (size_t)row * Dn + lane * 4;
    float4 v = *(const float4*)xr;
    float s = v.x + v.y + v.z + v.w;
#pragma unroll
    for (int o = 32; o > 0; o >>= 1) s += __shfl_xor(s, o, 64);
    const float mu = s * (1.f / Dn);
    const float dx = v.x - mu, dy = v.y - mu, dz = v.z - mu, dw = v.w - mu;
    float ss = dx * dx + dy * dy + dz * dz + dw * dw;
#pragma unroll
    for (int o = 32; o > 0; o >>= 1) ss += __shfl_xor(ss, o, 64);
    const float rstd = rsqrtf(ss * (1.f / Dn) + EPSV);
    const float4 gv = *(const float4*)(g + lane * 4);
    const float4 bv = *(const float4*)(b + lane * 4);
    float4 o4;
    o4.x = dx * rstd * gv.x + bv.x;
    o4.y = dy * rstd * gv.y + bv.y;
    o4.z = dz * rstd * gv.z + bv.z;
    o4.w = dw * rstd * gv.w + bv.w;
    *(float4*)(y + (size_t)row * Dn + lane * 4) = o4;
}

// ============ GEMM BIG: 128x128 tile, 8x8 microtile, reg-prefetch. N in {512,768} ============
// EPI: 0 = +bias (f32 out) ; 1 = silu(+bias) (f32 out) ; 3 = +bias, bf16 out
#define GBK 16

template <int EPI>
__global__ __launch_bounds__(256) void gemm_big_kernel(const float* __restrict__ A,
                                                       const float* __restrict__ Bw,
                                                       const float* __restrict__ bias,
                                                       float* __restrict__ C,
                                                       int M, int N, int K)
{
    __shared__ float As[GBK][132];   // transposed: As[k][m]
    __shared__ float Bs[GBK][132];
    const int tid  = threadIdx.x;
    const int tx   = tid & 15;          // col group: cols tx*8 .. tx*8+7
    const int ty   = tid >> 4;          // row group: rows ty*8 .. ty*8+7
    const int row0 = blockIdx.x * 128;
    const int col0 = blockIdx.y * 128;
    const int arow = tid >> 1;          // 0..127
    const int acol = (tid & 1) * 8;     // 0 or 8
    const int br   = tid >> 5;          // 0..7 (k-rows br and br+8)
    const int bc   = (tid & 31) * 4;    // 0..124
    const float* Ag = A + (size_t)(row0 + arow) * K + acol;
    const float* Bg = Bw + (size_t)br * N + col0 + bc;

    float4 pa0 = *(const float4*)(Ag);
    float4 pa1 = *(const float4*)(Ag + 4);
    float4 pb0 = *(const float4*)(Bg);
    float4 pb1 = *(const float4*)(Bg + (size_t)8 * N);

    float acc[8][8];
#pragma unroll
    for (int i = 0; i < 8; ++i)
#pragma unroll
        for (int j = 0; j < 8; ++j) acc[i][j] = 0.f;

    for (int k0 = 0; k0 < K; k0 += GBK) {
        As[acol + 0][arow] = pa0.x;
        As[acol + 1][arow] = pa0.y;
        As[acol + 2][arow] = pa0.z;
        As[acol + 3][arow] = pa0.w;
        As[acol + 4][arow] = pa1.x;
        As[acol + 5][arow] = pa1.y;
        As[acol + 6][arow] = pa1.z;
        As[acol + 7][arow] = pa1.w;
        *(float4*)&Bs[br][bc]     = pb0;
        *(float4*)&Bs[br + 8][bc] = pb1;
        __syncthreads();
        if (k0 + GBK < K) {
            pa0 = *(const float4*)(Ag + k0 + GBK);
            pa1 = *(const float4*)(Ag + k0 + GBK + 4);
            pb0 = *(const float4*)(Bg + (size_t)(k0 + GBK) * N);
            pb1 = *(const float4*)(Bg + (size_t)(k0 + GBK + 8) * N);
        }
#pragma unroll
        for (int kk = 0; kk < GBK; ++kk) {
            float av[8], bv[8];
            *(float4*)&av[0] = *(const float4*)&As[kk][ty * 8];
            *(float4*)&av[4] = *(const float4*)&As[kk][ty * 8 + 4];
            *(float4*)&bv[0] = *(const float4*)&Bs[kk][tx * 8];
            *(float4*)&bv[4] = *(const float4*)&Bs[kk][tx * 8 + 4];
#pragma unroll
            for (int i = 0; i < 8; ++i)
#pragma unroll
                for (int j = 0; j < 8; ++j) acc[i][j] = fmaf(av[i], bv[j], acc[i][j]);
        }
        __syncthreads();
    }

    const int c = col0 + tx * 8;
    const float4 bj0 = *(const float4*)(bias + c);
    const float4 bj1 = *(const float4*)(bias + c + 4);
#pragma unroll
    for (int i = 0; i < 8; ++i) {
        const int r = row0 + ty * 8 + i;
        float v[8];
        v[0] = acc[i][0] + bj0.x; v[1] = acc[i][1] + bj0.y;
        v[2] = acc[i][2] + bj0.z; v[3] = acc[i][3] + bj0.w;
        v[4] = acc[i][4] + bj1.x; v[5] = acc[i][5] + bj1.y;
        v[6] = acc[i][6] + bj1.z; v[7] = acc[i][7] + bj1.w;
        if (EPI == 1) {
#pragma unroll
            for (int j = 0; j < 8; ++j) v[j] *= sigmoidf_(v[j]);
        }
        if (EPI == 3) {
            bf16x8 o;
#pragma unroll
            for (int j = 0; j < 8; ++j) o[j] = (short)f2bfu(v[j]);
            *(bf16x8*)((unsigned short*)C + (size_t)r * N + c) = o;
        } else {
            float4 v0 = {v[0], v[1], v[2], v[3]};
            float4 v1 = {v[4], v[5], v[6], v[7]};
            *(float4*)(C + (size_t)r * N + c)     = v0;
            *(float4*)(C + (size_t)r * N + c + 4) = v1;
        }
    }
}

// ============ GEMM SMALL: 128x64 tile, 8x4 microtile, reg-prefetch. N=256 ============
// EPI: 0 = +bias ; 2 = res + scale*(+bias)
template <int EPI>
__global__ __launch_bounds__(256) void gemm_small_kernel(const float* __restrict__ A,
                                                         const float* __restrict__ Bw,
                                                         const float* __restrict__ bias,
                                                         const float* __restrict__ res,
                                                         float* __restrict__ C,
                                                         int M, int N, int K, float scale)
{
    __shared__ float As[GBK][132];
    __shared__ float Bs[GBK][68];
    const int tid  = threadIdx.x;
    const int tx   = tid & 15;
    const int ty   = tid >> 4;
    const int row0 = blockIdx.x * 128;
    const int col0 = blockIdx.y * 64;
    const int arow = tid >> 1;
    const int acol = (tid & 1) * 8;
    const int brow = tid >> 4;
    const int bcol = (tid & 15) * 4;
    const float* Ag = A + (size_t)(row0 + arow) * K + acol;
    const float* Bg = Bw + (size_t)brow * N + col0 + bcol;

    float4 pa0 = *(const float4*)(Ag);
    float4 pa1 = *(const float4*)(Ag + 4);
    float4 pb0 = *(const float4*)(Bg);

    float acc[8][4];
#pragma unroll
    for (int i = 0; i < 8; ++i)
#pragma unroll
        for (int j = 0; j < 4; ++j) acc[i][j] = 0.f;

    for (int k0 = 0; k0 < K; k0 += GBK) {
        As[acol + 0][arow] = pa0.x;
        As[acol + 1][arow] = pa0.y;
        As[acol + 2][arow] = pa0.z;
        As[acol + 3][arow] = pa0.w;
        As[acol + 4][arow] = pa1.x;
        As[acol + 5][arow] = pa1.y;
        As[acol + 6][arow] = pa1.z;
        As[acol + 7][arow] = pa1.w;
        *(float4*)&Bs[brow][bcol] = pb0;
        __syncthreads();
        if (k0 + GBK < K) {
            pa0 = *(const float4*)(Ag + k0 + GBK);
            pa1 = *(const float4*)(Ag + k0 + GBK + 4);
            pb0 = *(const float4*)(Bg + (size_t)(k0 + GBK) * N);
        }
#pragma unroll
        for (int kk = 0; kk < GBK; ++kk) {
            float av[8], bv[4];
            *(float4*)&av[0] = *(const float4*)&As[kk][ty * 8];
            *(float4*)&av[4] = *(const float4*)&As[kk][ty * 8 + 4];
            *(float4*)&bv[0] = *(const float4*)&Bs[kk][tx * 4];
#pragma unroll
            for (int i = 0; i < 8; ++i)
#pragma unroll
                for (int j = 0; j < 4; ++j) acc[i][j] = fmaf(av[i], bv[j], acc[i][j]);
        }
        __syncthreads();
    }

    const int c = col0 + tx * 4;
    const float4 bj = *(const float4*)(bias + c);
#pragma unroll
    for (int i = 0; i < 8; ++i) {
        const int r = row0 + ty * 8 + i;
        float4 v;
        v.x = acc[i][0] + bj.x; v.y = acc[i][1] + bj.y;
        v.z = acc[i][2] + bj.z; v.w = acc[i][3] + bj.w;
        if (EPI == 2) {
            const float4 rv = *(const float4*)(res + (size_t)r * N + c);
            v.x = rv.x + scale * v.x; v.y = rv.y + scale * v.y;
            v.z = rv.z + scale * v.z; v.w = rv.w + scale * v.w;
        }
        *(float4*)(C + (size_t)r * N + c) = v;
    }
}

// ---------------- Attention: bf16 MFMA flash. qkv bf16 [B,T,768], out f32 [B,T,256] ----------------
// Block: 256 thr = 4 waves; wave owns 32 q-rows (2 q-tiles of 16). kv chunks of 64.
// MFMA 16x16x32 layouts: A: row=l&15, k=(l>>4)*8+i ; B: col=l&15, k=(l>>4)*8+i ;
// C/D: col=l&15, row=(l>>4)*4+r   [m89-verified]
__global__ __launch_bounds__(256) void attn_mfma_kernel(const unsigned short* __restrict__ qkv,
                                                        float* __restrict__ out)
{
    __shared__ unsigned short Kl[64][40];       // K rows, pad 40 -> 2-way (free)
    __shared__ unsigned short Vt[32][72];       // V^T [d][kv], pad 72 -> 2-way
    __shared__ unsigned short Pl[4][16][72];    // per-wave P [q][kv], pad 72

    const int tid = threadIdx.x;
    const int w   = tid >> 6;
    const int l   = tid & 63;
    const int g   = l >> 4;
    const int q16 = l & 15;
    const int b   = blockIdx.y >> 3;
    const int h   = blockIdx.y & 7;
    const int q0  = blockIdx.x * 128 + w * 32;
    const unsigned short* base = qkv + (size_t)b * Tn * 768;

    // Q fragments (A-operand): lane l -> row q0+u*16+(l&15), k-cols g*8..g*8+7
    bf16x8 qf[2];
#pragma unroll
    for (int u = 0; u < 2; ++u)
        qf[u] = *(const bf16x8*)(base + (size_t)(q0 + u * 16 + q16) * 768 + h * 32 + g * 8);

    f32x4 O[2][2];
    float mrun[2][4], lrun[2][4];
#pragma unroll
    for (int u = 0; u < 2; ++u)
#pragma unroll
        for (int t = 0; t < 2; ++t) { O[u][t].x = 0.f; O[u][t].y = 0.f; O[u][t].z = 0.f; O[u][t].w = 0.f; }
#pragma unroll
    for (int u = 0; u < 2; ++u)
#pragma unroll
        for (int r = 0; r < 4; ++r) { mrun[u][r] = 0.f; lrun[u][r] = 0.f; }

    const float cs = 0.25505392367033404f;   // (1/sqrt(32)) * log2(e)

    const int kvr = tid >> 2;         // staging: row 0..63
    const int dsg = (tid & 3) * 8;    // staging: d-seg 0/8/16/24

    for (int c0 = 0; c0 < Tn; c0 += 64) {
        __syncthreads();   // protect LDS from previous chunk's readers
        {
            const unsigned short* kp = base + (size_t)(c0 + kvr) * 768 + 256 + h * 32 + dsg;
            bf16x8 kk = *(const bf16x8*)kp;
            bf16x8 vv = *(const bf16x8*)(kp + 256);
            *(bf16x8*)&Kl[kvr][dsg] = kk;
#pragma unroll
            for (int i = 0; i < 8; ++i) Vt[dsg + i][kvr] = (unsigned short)vv[i];
        }
        __syncthreads();

        // K fragments (B-operand): col=kv=t*16+(l&15), k=d=g*8+i
        bf16x8 kb[4];
#pragma unroll
        for (int t = 0; t < 4; ++t)
            kb[t] = *(const bf16x8*)&Kl[t * 16 + q16][g * 8];
        // V fragments (B-operand for PV): col=d=ht*16+(l&15), k=kv=c*32+g*8+i
        bf16x8 vb[2][2];
#pragma unroll
        for (int ht = 0; ht < 2; ++ht)
#pragma unroll
            for (int c = 0; c < 2; ++c)
                vb[ht][c] = *(const bf16x8*)&Vt[ht * 16 + q16][c * 32 + g * 8];

#pragma unroll
        for (int u = 0; u < 2; ++u) {
            // S = Q K^T (scaled to log2 domain)
            float p[4][4];
#pragma unroll
            for (int t = 0; t < 4; ++t) {
                f32x4 z = {0.f, 0.f, 0.f, 0.f};
                f32x4 s = __builtin_amdgcn_mfma_f32_16x16x32_bf16(qf[u], kb[t], z, 0, 0, 0);
#pragma unroll
                for (int r = 0; r < 4; ++r) p[t][r] = s[r] * cs;
            }
            // row max (across 4 t-cols, then across 16 lanes of the col-group)
            float mx[4];
#pragma unroll
            for (int r = 0; r < 4; ++r)
                mx[r] = fmaxf(fmaxf(p[0][r], p[1][r]), fmaxf(p[2][r], p[3][r]));
#pragma unroll
            for (int o = 1; o < 16; o <<= 1)
#pragma unroll
                for (int r = 0; r < 4; ++r) mx[r] = fmaxf(mx[r], __shfl_xor(mx[r], o, 64));
            // defer-max: rescale only if max grew past threshold (cold for this data)
            float wg = mx[0] - mrun[u][0];
#pragma unroll
            for (int r = 1; r < 4; ++r) wg = fmaxf(wg, mx[r] - mrun[u][r]);
            if (__any(wg > 11.f)) {
#pragma unroll
                for (int r = 0; r < 4; ++r) {
                    const float mn = fmaxf(mrun[u][r], mx[r]);
                    const float f  = exp2f(mrun[u][r] - mn);
                    lrun[u][r] *= f;
                    O[u][0][r] *= f;
                    O[u][1][r] *= f;
                    mrun[u][r] = mn;
                }
            }
            // P = 2^(z-m); accumulate per-lane partial row-sums; write P (bf16) to wave-private LDS
#pragma unroll
            for (int t = 0; t < 4; ++t)
#pragma unroll
                for (int r = 0; r < 4; ++r) {
                    const float pe = exp2f(p[t][r] - mrun[u][r]);
                    lrun[u][r] += pe;
                    Pl[w][g * 4 + r][t * 16 + q16] = f2bfu(pe);
                }
            // PV: A = P (row=q=l&15, k=kv), B = V^T frags
            bf16x8 pa[2];
#pragma unroll
            for (int c = 0; c < 2; ++c)
                pa[c] = *(const bf16x8*)&Pl[w][q16][c * 32 + g * 8];
#pragma unroll
            for (int ht = 0; ht < 2; ++ht) {
                O[u][ht] = __builtin_amdgcn_mfma_f32_16x16x32_bf16(pa[0], vb[ht][0], O[u][ht], 0, 0, 0);
                O[u][ht] = __builtin_amdgcn_mfma_f32_16x16x32_bf16(pa[1], vb[ht][1], O[u][ht], 0, 0, 0);
            }
        }
    }

    // finalize: reduce l across the 16 lanes of each row-group, normalize, store
#pragma unroll
    for (int u = 0; u < 2; ++u) {
#pragma unroll
        for (int o = 1; o < 16; o <<= 1)
#pragma unroll
            for (int r = 0; r < 4; ++r) lrun[u][r] += __shfl_xor(lrun[u][r], o, 64);
#pragma unroll
        for (int r = 0; r < 4; ++r) {
            const float inv = 1.f / lrun[u][r];
            const int row = b * Tn + q0 + u * 16 + g * 4 + r;
#pragma unroll
            for (int ht = 0; ht < 2; ++ht)
                out[(size_t)row * Dn + h * 32 + ht * 16 + q16] = O[u][ht][r] * inv;
        }
    }
}

// ---------------- GLU: [B,T,512] -> [B,T,256], a*sigmoid(g) ----------------
__global__ __launch_bounds__(256) void glu_kernel(const float* __restrict__ h,
                                                  float* __restrict__ outp)
{
    const size_t i   = (size_t)blockIdx.x * 256 + threadIdx.x;
    const size_t row = i / (Dn / 4);
    const int    c4  = (int)(i % (Dn / 4)) * 4;
    const float* hp  = h + row * (2 * Dn);
    const float4 a = *(const float4*)(hp + c4);
    const float4 g = *(const float4*)(hp + Dn + c4);
    float4 r;
    r.x = a.x * sigmoidf_(g.x);
    r.y = a.y * sigmoidf_(g.y);
    r.z = a.z * sigmoidf_(g.z);
    r.w = a.w * sigmoidf_(g.w);
    *(float4*)(outp + row * Dn + c4) = r;
}

// ---------------- Depthwise conv over time, K=31, layout [B,T,D] ----------------
__global__ __launch_bounds__(256) void dwconv_kernel(const float* __restrict__ in,
                                                     const float* __restrict__ w,
                                                     const float* __restrict__ wb,
                                                     float* __restrict__ outp)
{
    const int d  = threadIdx.x;
    const int b  = blockIdx.y;
    const int t0 = blockIdx.x * 8;
    float wr[KW];
#pragma unroll
    for (int k = 0; k < KW; ++k) wr[k] = w[d * KW + k];
    const float bias = wb[d];
    const float* bin  = in + (size_t)b * Tn * Dn + d;
    float* bout       = outp + (size_t)b * Tn * Dn + d;
    if (t0 >= (KW / 2) + 1 && t0 + 8 + KW / 2 <= Tn) {
        for (int i = 0; i < 8; ++i) {
            const int t = t0 + i;
            float s = bias;
#pragma unroll
            for (int k = 0; k < KW; ++k) s = fmaf(bin[(size_t)(t + k - KW / 2) * Dn], wr[k], s);
            bout[(size_t)t * Dn] = s;
        }
    } else {
        for (int i = 0; i < 8; ++i) {
            const int t = t0 + i;
            float s = bias;
#pragma unroll
            for (int k = 0; k < KW; ++k) {
                const int tt = t + k - KW / 2;
                if (tt >= 0 && tt < Tn) s = fmaf(bin[(size_t)tt * Dn], wr[k], s);
            }
            bout[(size_t)t * Dn] = s;
        }
    }
}

// ---------------- BatchNorm stats, 2-stage coalesced ----------------
__global__ __launch_bounds__(256) void bnpart_kernel(const float* __restrict__ in,
                                                     float* __restrict__ part)
{
    const int d  = threadIdx.x;
    const int bk = blockIdx.x;
    float s = 0.f, ss = 0.f;
    const float* p = in + (size_t)bk * 32 * Dn + d;
    for (int t = 0; t < 32; ++t) {
        const float v = p[(size_t)t * Dn];
        s += v;
        ss = fmaf(v, v, ss);
    }
    part[bk * 512 + d]       = s;
    part[bk * 512 + 256 + d] = ss;
}

__global__ __launch_bounds__(256) void bnfin_kernel(const float* __restrict__ part,
                                                    float* __restrict__ meanp,
                                                    float* __restrict__ rstdp)
{
    const int d = threadIdx.x;
    float s = 0.f, ss = 0.f;
    for (int k = 0; k < 256; ++k) {
        s  += part[k * 512 + d];
        ss += part[k * 512 + 256 + d];
    }
    const float mu  = s * (1.f / NTOK);
    const float var = ss * (1.f / NTOK) - mu * mu;
    meanp[d] = mu;
    rstdp[d] = rsqrtf(var + EPSV);
}

// ---------------- BN apply + SiLU ----------------
__global__ __launch_bounds__(256) void bnsilu_kernel(const float* __restrict__ in,
                                                     const float* __restrict__ meanp,
                                                     const float* __restrict__ rstdp,
                                                     const float* __restrict__ g,
                                                     const float* __restrict__ bb,
                                                     float* __restrict__ outp)
{
    const size_t idx = ((size_t)blockIdx.x * 256 + threadIdx.x) * 4;
    const int d = (int)(idx & (Dn - 1));
    const float4 v = *(const float4*)(in + idx);
    float4 r;
    {
        float t;
        t = (v.x - meanp[d + 0]) * rstdp[d + 0] * g[d + 0] + bb[d + 0]; r.x = t * sigmoidf_(t);
        t = (v.y - meanp[d + 1]) * rstdp[d + 1] * g[d + 1] + bb[d + 1]; r.y = t * sigmoidf_(t);
        t = (v.z - meanp[d + 2]) * rstdp[d + 2] * g[d + 2] + bb[d + 2]; r.z = t * sigmoidf_(t);
        t = (v.w - meanp[d + 3]) * rstdp[d + 3] * g[d + 3] + bb[d + 3]; r.w = t * sigmoidf_(t);
    }
    *(float4*)(outp + idx) = r;
}

// ---------------- launch ----------------
extern "C" void kernel_launch(void* const* d_in, const int* in_sizes, int n_in,
                              void* d_out, int out_size, void* d_ws, size_t ws_size,
                              hipStream_t stream)
{
    const float* x         = (const float*)d_in[0];
    const float* ff1_ln_g  = (const float*)d_in[1];
    const float* ff1_ln_b  = (const float*)d_in[2];
    const float* ff1_w1    = (const float*)d_in[3];
    const float* ff1_b1    = (const float*)d_in[4];
    const float* ff1_w2    = (const float*)d_in[5];
    const float* ff1_b2    = (const float*)d_in[6];
    const float* mhsa_ln_g = (const float*)d_in[7];
    const float* mhsa_ln_b = (const float*)d_in[8];
    const float* qkv_w     = (const float*)d_in[9];
    const float* qkv_b     = (const float*)d_in[10];
    const float* out_w     = (const float*)d_in[11];
    const float* out_b     = (const float*)d_in[12];
    const float* conv_ln_g = (const float*)d_in[13];
    const float* conv_ln_b = (const float*)d_in[14];
    const float* pw1_w     = (const float*)d_in[15];
    const float* pw1_b     = (const float*)d_in[16];
    const float* dw_w      = (const float*)d_in[17];
    const float* dw_b      = (const float*)d_in[18];
    const float* bn_g      = (const float*)d_in[19];
    const float* bn_b      = (const float*)d_in[20];
    const float* pw2_w     = (const float*)d_in[21];
    const float* pw2_b     = (const float*)d_in[22];
    const float* ff2_ln_g  = (const float*)d_in[23];
    const float* ff2_ln_b  = (const float*)d_in[24];
    const float* ff2_w1    = (const float*)d_in[25];
    const float* ff2_b1    = (const float*)d_in[26];
    const float* ff2_w2    = (const float*)d_in[27];
    const float* ff2_b2    = (const float*)d_in[28];
    const float* fin_ln_g  = (const float*)d_in[29];
    const float* fin_ln_b  = (const float*)d_in[30];

    float* ws   = (float*)d_ws;
    float* R    = ws;                 // residual stream [8192,256]
    float* Nb   = R + 2097152;        // LN output      [8192,256]
    float* HQ   = Nb + 2097152;       // FF hidden f32 [8192,512] / QKV bf16 [8192,768] (time-shared)
    float* part = HQ + 6291456;       // BN partials [256][512]
    float* mean = part + 131072;      // [256]
    float* rstd = mean + 256;         // [256]
    float* Cb   = Nb;                 // conv output aliases Nb (Nb dead after pw1 gemm)
    float* Ab   = (float*)d_out;      // [8192,256] scratch (attn/GLU/BN out), final output

    const dim3 blk(256);

    // ---- FF1 ----
    ln_kernel<<<NTOK / 4, blk, 0, stream>>>(x, ff1_ln_g, ff1_ln_b, Nb);
    gemm_big_kernel<1><<<dim3(64, 4), blk, 0, stream>>>(Nb, ff1_w1, ff1_b1, HQ, NTOK, 512, 256);
    gemm_small_kernel<2><<<dim3(64, 4), blk, 0, stream>>>(HQ, ff1_w2, ff1_b2, x, R, NTOK, 256, 512, 0.5f);

    // ---- MHSA ----
    ln_kernel<<<NTOK / 4, blk, 0, stream>>>(R, mhsa_ln_g, mhsa_ln_b, Nb);
    gemm_big_kernel<3><<<dim3(64, 6), blk, 0, stream>>>(Nb, qkv_w, qkv_b, HQ, NTOK, 768, 256);  // bf16 out
    attn_mfma_kernel<<<dim3(16, 32), blk, 0, stream>>>((const unsigned short*)HQ, Ab);
    gemm_small_kernel<2><<<dim3(64, 4), blk, 0, stream>>>(Ab, out_w, out_b, R, R, NTOK, 256, 256, 1.f);

    // ---- Conv module ----
    ln_kernel<<<NTOK / 4, blk, 0, stream>>>(R, conv_ln_g, conv_ln_b, Nb);
    gemm_big_kernel<0><<<dim3(64, 4), blk, 0, stream>>>(Nb, pw1_w, pw1_b, HQ, NTOK, 512, 256);
    glu_kernel<<<NTOK * Dn / 4 / 256, blk, 0, stream>>>(HQ, Ab);
    dwconv_kernel<<<dim3(Tn / 8, Bn), blk, 0, stream>>>(Ab, dw_w, dw_b, Cb);
    bnpart_kernel<<<256, blk, 0, stream>>>(Cb, part);
    bnfin_kernel<<<1, blk, 0, stream>>>(part, mean, rstd);
    bnsilu_kernel<<<NTOK * Dn / 4 / 256, blk, 0, stream>>>(Cb, mean, rstd, bn_g, bn_b, Ab);
    gemm_small_kernel<2><<<dim3(64, 4), blk, 0, stream>>>(Ab, pw2_w, pw2_b, R, R, NTOK, 256, 256, 1.f);

    // ---- FF2 ----
    ln_kernel<<<NTOK / 4, blk, 0, stream>>>(R, ff2_ln_g, ff2_ln_b, Nb);
    gemm_big_kernel<1><<<dim3(64, 4), blk, 0, stream>>>(Nb, ff2_w1, ff2_b1, HQ, NTOK, 512, 256);
    gemm_small_kernel<2><<<dim3(64, 4), blk, 0, stream>>>(HQ, ff2_w2, ff2_b2, R, R, NTOK, 256, 512, 0.5f);

    // ---- Final LN ----
    ln_kernel<<<NTOK / 4, blk, 0, stream>>>(R, fin_ln_g, fin_ln_b, (float*)d_out);
}

// Round 4
// 392.804 us; speedup vs baseline: 3.4609x; 1.4312x over previous
//
#include <hip/hip_runtime.h>
#include <hip/hip_bf16.h>

// Conformer block. B=4, T=2048, D=256, H=8, HD=32, K=31.
// All matmuls: bf16 MFMA 16x16x32, fp32 accumulate. LN/BN/residual/conv: fp32.
#define Bn 4
#define Tn 2048
#define Dn 256
#define Hn 8
#define HDn 32
#define KW 31
#define EPSV 1e-5f
#define NTOK (Bn * Tn)   // 8192 tokens

typedef __attribute__((ext_vector_type(8))) short bf16x8;   // 8 bf16 = 4 VGPR (MFMA A/B frag)
typedef __attribute__((ext_vector_type(4))) float f32x4;    // MFMA C/D frag
typedef unsigned short ushort_t;

__device__ __forceinline__ float sigmoidf_(float x) { return 1.f / (1.f + __expf(-x)); }
__device__ __forceinline__ unsigned short f2bfu(float f) {
    __hip_bfloat16 h = __float2bfloat16(f);
    unsigned short u; __builtin_memcpy(&u, &h, 2); return u;
}

// ---------------- LayerNorm (f32 in): one wave per row; OUT template: 0=f32, 1=bf16 ----------------
template <int OUTBF>
__global__ __launch_bounds__(256) void ln_kernel(const float* __restrict__ x,
                                                 const float* __restrict__ g,
                                                 const float* __restrict__ b,
                                                 void* __restrict__ yp)
{
    const int row  = blockIdx.x * 4 + (threadIdx.x >> 6);
    const int lane = threadIdx.x & 63;
    const float* xr = x + (size_t)row * Dn + lane * 4;
    float4 v = *(const float4*)xr;
    float s = v.x + v.y + v.z + v.w;
#pragma unroll
    for (int o = 32; o > 0; o >>= 1) s += __shfl_xor(s, o, 64);
    const float mu = s * (1.f / Dn);
    const float dx = v.x - mu, dy = v.y - mu, dz = v.z - mu, dw = v.w - mu;
    float ss = dx * dx + dy * dy + dz * dz + dw * dw;
#pragma unroll
    for (int o = 32; o > 0; o >>= 1) ss += __shfl_xor(ss, o, 64);
    const float rstd = rsqrtf(ss * (1.f / Dn) + EPSV);
    const float4 gv = *(const float4*)(g + lane * 4);
    const float4 bv = *(const float4*)(b + lane * 4);
    float o0 = dx * rstd * gv.x + bv.x;
    float o1 = dy * rstd * gv.y + bv.y;
    float o2 = dz * rstd * gv.z + bv.z;
    float o3 = dw * rstd * gv.w + bv.w;
    if (OUTBF) {
        ushort4 o4;
        o4.x = f2bfu(o0); o4.y = f2bfu(o1); o4.z = f2bfu(o2); o4.w = f2bfu(o3);
        *(ushort4*)((ushort_t*)yp + (size_t)row * Dn + lane * 4) = o4;
    } else {
        float4 o4 = {o0, o1, o2, o3};
        *(float4*)((float*)yp + (size_t)row * Dn + lane * 4) = o4;
    }
}

// ---------------- Weight prep: [K,N] f32 -> [N,K] bf16 (8 weights, one launch) ----------------
struct WP {
    const float* s[8];
    unsigned     off[8];
    int          Kd[8];
    int          Nd[8];
};

__global__ __launch_bounds__(256) void wprep_kernel(WP p, ushort_t* __restrict__ wb)
{
    const int z = blockIdx.z;
    const int N = p.Nd[z], K = p.Kd[z];
    const int n0 = blockIdx.x * 64, k0 = blockIdx.y * 32;
    if (n0 >= N || k0 >= K) return;
    const float* src = p.s[z];
    ushort_t* dst = wb + p.off[z];
    const int nl = threadIdx.x & 63, kq = threadIdx.x >> 6;
    const int n = n0 + nl;
    const int kb = k0 + kq * 8;
    bf16x8 o;
#pragma unroll
    for (int i = 0; i < 8; ++i) o[i] = (short)f2bfu(src[(size_t)(kb + i) * N + n]);
    *(bf16x8*)(dst + (size_t)n * K + kb) = o;
}

// ============ bf16 MFMA GEMM: C[M,N] = epi(A[M,K] @ Bt[N,K]^T + bias) ============
// Tile 128x128x32. 256 thr = 4 waves (2x2), wave tile 64x64 = 4x4 MFMA 16x16x32.
// LDS is FRAGMENT-MAJOR: block bi holds lane l's 16B frag at base+bi*1024+l*16
// -> lane-linear ds_write/ds_read = zero bank conflicts (permutation folded into global addr).
// EPI: 0 = bias -> bf16 ; 1 = silu(bias) -> bf16 ; 2 = res + scale*(bias+x) -> f32 ; 3 = bias -> f32
template <int EPI>
__global__ __launch_bounds__(256) void bgemm_kernel(const ushort_t* __restrict__ A,
                                                    const ushort_t* __restrict__ Bt,
                                                    const float* __restrict__ bias,
                                                    const float* __restrict__ res,
                                                    void* __restrict__ Cp,
                                                    int N, int K, float scale)
{
    __shared__ ushort_t Af[8][64][8];   // 8 KB, frag-major
    __shared__ ushort_t Bf[8][64][8];   // 8 KB
    const int tid = threadIdx.x;
    const int w   = tid >> 6;
    const int l   = tid & 63;
    const int g   = l >> 4;
    const int q16 = l & 15;
    const int wm  = w >> 1;
    const int wn  = w & 1;
    const int row0 = blockIdx.x * 128;
    const int col0 = blockIdx.y * 128;

    // staging global sources (lane-permuted so LDS is frag-major): blocks 2w, 2w+1
    const ushort_t* ga0 = A  + (size_t)(row0 + (2 * w + 0) * 16 + q16) * K + g * 8;
    const ushort_t* ga1 = A  + (size_t)(row0 + (2 * w + 1) * 16 + q16) * K + g * 8;
    const ushort_t* gb0 = Bt + (size_t)(col0 + (2 * w + 0) * 16 + q16) * K + g * 8;
    const ushort_t* gb1 = Bt + (size_t)(col0 + (2 * w + 1) * 16 + q16) * K + g * 8;

    f32x4 acc[4][4];
#pragma unroll
    for (int mt = 0; mt < 4; ++mt)
#pragma unroll
        for (int nt = 0; nt < 4; ++nt) { acc[mt][nt].x = 0.f; acc[mt][nt].y = 0.f; acc[mt][nt].z = 0.f; acc[mt][nt].w = 0.f; }

    bf16x8 sa0 = *(const bf16x8*)ga0;
    bf16x8 sa1 = *(const bf16x8*)ga1;
    bf16x8 sb0 = *(const bf16x8*)gb0;
    bf16x8 sb1 = *(const bf16x8*)gb1;

    const int NKT = K >> 5;
    for (int kt = 0; kt < NKT; ++kt) {
        __syncthreads();                       // previous readers done
        *(bf16x8*)&Af[2 * w + 0][l][0] = sa0;  // lane-linear: conflict-free
        *(bf16x8*)&Af[2 * w + 1][l][0] = sa1;
        *(bf16x8*)&Bf[2 * w + 0][l][0] = sb0;
        *(bf16x8*)&Bf[2 * w + 1][l][0] = sb1;
        if (kt + 1 < NKT) {                    // prefetch next K-tile; latency hides under MFMA
            const int k = (kt + 1) * 32;
            sa0 = *(const bf16x8*)(ga0 + k);
            sa1 = *(const bf16x8*)(ga1 + k);
            sb0 = *(const bf16x8*)(gb0 + k);
            sb1 = *(const bf16x8*)(gb1 + k);
        }
        __syncthreads();
        bf16x8 af[4], bb[4];
#pragma unroll
        for (int mt = 0; mt < 4; ++mt) af[mt] = *(const bf16x8*)&Af[wm * 4 + mt][l][0];
#pragma unroll
        for (int nt = 0; nt < 4; ++nt) bb[nt] = *(const bf16x8*)&Bf[wn * 4 + nt][l][0];
#pragma unroll
        for (int mt = 0; mt < 4; ++mt)
#pragma unroll
            for (int nt = 0; nt < 4; ++nt)
                acc[mt][nt] = __builtin_amdgcn_mfma_f32_16x16x32_bf16(af[mt], bb[nt], acc[mt][nt], 0, 0, 0);
    }

    // epilogue: C/D layout col=l&15, row=g*4+r
#pragma unroll
    for (int nt = 0; nt < 4; ++nt) {
        const int col = col0 + (wn * 4 + nt) * 16 + q16;
        const float bj = bias[col];
#pragma unroll
        for (int mt = 0; mt < 4; ++mt) {
            const int rowb = row0 + (wm * 4 + mt) * 16 + g * 4;
#pragma unroll
            for (int r = 0; r < 4; ++r) {
                float v = acc[mt][nt][r] + bj;
                const size_t idx = (size_t)(rowb + r) * N + col;
                if (EPI == 1) v *= sigmoidf_(v);
                if (EPI == 0 || EPI == 1) {
                    ((ushort_t*)Cp)[idx] = f2bfu(v);
                } else if (EPI == 2) {
                    ((float*)Cp)[idx] = res[idx] + scale * v;
                } else {
                    ((float*)Cp)[idx] = v;
                }
            }
        }
    }
}

// ---------------- Attention: bf16 MFMA flash. qkv bf16 [B,T,768], out bf16 [B,T,256] ----------------
__global__ __launch_bounds__(256) void attn_mfma_kernel(const ushort_t* __restrict__ qkv,
                                                        ushort_t* __restrict__ out)
{
    __shared__ ushort_t Kl[64][40];       // K rows
    __shared__ ushort_t Vt[32][72];       // V^T [d][kv], col ^= (d&24)<<1 (write-conflict-free)
    __shared__ ushort_t Pl[4][16][72];    // per-wave P [q][kv], col ^= (row>>2)<<4

    const int tid = threadIdx.x;
    const int w   = tid >> 6;
    const int l   = tid & 63;
    const int g   = l >> 4;
    const int q16 = l & 15;
    const int b   = blockIdx.y >> 3;
    const int h   = blockIdx.y & 7;
    const int q0  = blockIdx.x * 128 + w * 32;
    const ushort_t* base = qkv + (size_t)b * Tn * 768;

    bf16x8 qf[2];
#pragma unroll
    for (int u = 0; u < 2; ++u)
        qf[u] = *(const bf16x8*)(base + (size_t)(q0 + u * 16 + q16) * 768 + h * 32 + g * 8);

    f32x4 O[2][2];
    float mrun[2][4], lrun[2][4];
#pragma unroll
    for (int u = 0; u < 2; ++u)
#pragma unroll
        for (int t = 0; t < 2; ++t) { O[u][t].x = 0.f; O[u][t].y = 0.f; O[u][t].z = 0.f; O[u][t].w = 0.f; }
#pragma unroll
    for (int u = 0; u < 2; ++u)
#pragma unroll
        for (int r = 0; r < 4; ++r) { mrun[u][r] = 0.f; lrun[u][r] = 0.f; }

    const float cs = 0.25505392367033404f;   // (1/sqrt(32)) * log2(e)

    const int kvr = tid >> 2;         // staging row 0..63
    const int dsg = (tid & 3) * 8;    // staging d-seg 0/8/16/24

    for (int c0 = 0; c0 < Tn; c0 += 64) {
        __syncthreads();
        {
            const ushort_t* kp = base + (size_t)(c0 + kvr) * 768 + 256 + h * 32 + dsg;
            bf16x8 kk = *(const bf16x8*)kp;
            bf16x8 vv = *(const bf16x8*)(kp + 256);
            *(bf16x8*)&Kl[kvr][dsg] = kk;
            const int vcol = kvr ^ (dsg << 1);   // (dsg+i)&24 == dsg for i<8
#pragma unroll
            for (int i = 0; i < 8; ++i) Vt[dsg + i][vcol] = (ushort_t)vv[i];
        }
        __syncthreads();

        bf16x8 kb[4];
#pragma unroll
        for (int t = 0; t < 4; ++t)
            kb[t] = *(const bf16x8*)&Kl[t * 16 + q16][g * 8];
        bf16x8 vb[2][2];
#pragma unroll
        for (int ht = 0; ht < 2; ++ht) {
            const int d = ht * 16 + q16;
#pragma unroll
            for (int c = 0; c < 2; ++c)
                vb[ht][c] = *(const bf16x8*)&Vt[d][(c * 32 + g * 8) ^ ((d & 24) << 1)];
        }

#pragma unroll
        for (int u = 0; u < 2; ++u) {
            float p[4][4];
#pragma unroll
            for (int t = 0; t < 4; ++t) {
                f32x4 z = {0.f, 0.f, 0.f, 0.f};
                f32x4 s = __builtin_amdgcn_mfma_f32_16x16x32_bf16(qf[u], kb[t], z, 0, 0, 0);
#pragma unroll
                for (int r = 0; r < 4; ++r) p[t][r] = s[r] * cs;
            }
            float mx[4];
#pragma unroll
            for (int r = 0; r < 4; ++r)
                mx[r] = fmaxf(fmaxf(p[0][r], p[1][r]), fmaxf(p[2][r], p[3][r]));
#pragma unroll
            for (int o = 1; o < 16; o <<= 1)
#pragma unroll
                for (int r = 0; r < 4; ++r) mx[r] = fmaxf(mx[r], __shfl_xor(mx[r], o, 64));
            float wg = mx[0] - mrun[u][0];
#pragma unroll
            for (int r = 1; r < 4; ++r) wg = fmaxf(wg, mx[r] - mrun[u][r]);
            if (__any(wg > 11.f)) {
#pragma unroll
                for (int r = 0; r < 4; ++r) {
                    const float mn = fmaxf(mrun[u][r], mx[r]);
                    const float f  = exp2f(mrun[u][r] - mn);
                    lrun[u][r] *= f;
                    O[u][0][r] *= f;
                    O[u][1][r] *= f;
                    mrun[u][r] = mn;
                }
            }
#pragma unroll
            for (int t = 0; t < 4; ++t)
#pragma unroll
                for (int r = 0; r < 4; ++r) {
                    const float pe = exp2f(p[t][r] - mrun[u][r]);
                    lrun[u][r] += pe;
                    Pl[w][g * 4 + r][(t * 16 + q16) ^ (g << 4)] = f2bfu(pe);
                }
            bf16x8 pa[2];
#pragma unroll
            for (int c = 0; c < 2; ++c)
                pa[c] = *(const bf16x8*)&Pl[w][q16][(c * 32 + g * 8) ^ ((q16 >> 2) << 4)];
#pragma unroll
            for (int ht = 0; ht < 2; ++ht) {
                O[u][ht] = __builtin_amdgcn_mfma_f32_16x16x32_bf16(pa[0], vb[ht][0], O[u][ht], 0, 0, 0);
                O[u][ht] = __builtin_amdgcn_mfma_f32_16x16x32_bf16(pa[1], vb[ht][1], O[u][ht], 0, 0, 0);
            }
        }
    }

#pragma unroll
    for (int u = 0; u < 2; ++u) {
#pragma unroll
        for (int o = 1; o < 16; o <<= 1)
#pragma unroll
            for (int r = 0; r < 4; ++r) lrun[u][r] += __shfl_xor(lrun[u][r], o, 64);
#pragma unroll
        for (int r = 0; r < 4; ++r) {
            const float inv = 1.f / lrun[u][r];
            const int row = b * Tn + q0 + u * 16 + g * 4 + r;
#pragma unroll
            for (int ht = 0; ht < 2; ++ht)
                out[(size_t)row * Dn + h * 32 + ht * 16 + q16] = f2bfu(O[u][ht][r] * inv);
        }
    }
}

// ---------------- GLU: [B,T,512] f32 -> [B,T,256] f32 ----------------
__global__ __launch_bounds__(256) void glu_kernel(const float* __restrict__ h,
                                                  float* __restrict__ outp)
{
    const size_t i   = (size_t)blockIdx.x * 256 + threadIdx.x;
    const size_t row = i / (Dn / 4);
    const int    c4  = (int)(i % (Dn / 4)) * 4;
    const float* hp  = h + row * (2 * Dn);
    const float4 a = *(const float4*)(hp + c4);
    const float4 g = *(const float4*)(hp + Dn + c4);
    float4 r;
    r.x = a.x * sigmoidf_(g.x);
    r.y = a.y * sigmoidf_(g.y);
    r.z = a.z * sigmoidf_(g.z);
    r.w = a.w * sigmoidf_(g.w);
    *(float4*)(outp + row * Dn + c4) = r;
}

// ---------------- Depthwise conv over time, K=31, layout [B,T,D] f32 ----------------
__global__ __launch_bounds__(256) void dwconv_kernel(const float* __restrict__ in,
                                                     const float* __restrict__ w,
                                                     const float* __restrict__ wb,
                                                     float* __restrict__ outp)
{
    const int d  = threadIdx.x;
    const int b  = blockIdx.y;
    const int t0 = blockIdx.x * 8;
    float wr[KW];
#pragma unroll
    for (int k = 0; k < KW; ++k) wr[k] = w[d * KW + k];
    const float bias = wb[d];
    const float* bin  = in + (size_t)b * Tn * Dn + d;
    float* bout       = outp + (size_t)b * Tn * Dn + d;
    if (t0 >= (KW / 2) + 1 && t0 + 8 + KW / 2 <= Tn) {
        for (int i = 0; i < 8; ++i) {
            const int t = t0 + i;
            float s = bias;
#pragma unroll
            for (int k = 0; k < KW; ++k) s = fmaf(bin[(size_t)(t + k - KW / 2) * Dn], wr[k], s);
            bout[(size_t)t * Dn] = s;
        }
    } else {
        for (int i = 0; i < 8; ++i) {
            const int t = t0 + i;
            float s = bias;
#pragma unroll
            for (int k = 0; k < KW; ++k) {
                const int tt = t + k - KW / 2;
                if (tt >= 0 && tt < Tn) s = fmaf(bin[(size_t)tt * Dn], wr[k], s);
            }
            bout[(size_t)t * Dn] = s;
        }
    }
}

// ---------------- BatchNorm stats, 2-stage coalesced ----------------
__global__ __launch_bounds__(256) void bnpart_kernel(const float* __restrict__ in,
                                                     float* __restrict__ part)
{
    const int d  = threadIdx.x;
    const int bk = blockIdx.x;
    float s = 0.f, ss = 0.f;
    const float* p = in + (size_t)bk * 32 * Dn + d;
    for (int t = 0; t < 32; ++t) {
        const float v = p[(size_t)t * Dn];
        s += v;
        ss = fmaf(v, v, ss);
    }
    part[bk * 512 + d]       = s;
    part[bk * 512 + 256 + d] = ss;
}

__global__ __launch_bounds__(256) void bnfin_kernel(const float* __restrict__ part,
                                                    float* __restrict__ meanp,
                                                    float* __restrict__ rstdp)
{
    const int d = threadIdx.x;
    float s = 0.f, ss = 0.f;
    for (int k = 0; k < 256; ++k) {
        s  += part[k * 512 + d];
        ss += part[k * 512 + 256 + d];
    }
    const float mu  = s * (1.f / NTOK);
    const float var = ss * (1.f / NTOK) - mu * mu;
    meanp[d] = mu;
    rstdp[d] = rsqrtf(var + EPSV);
}

// ---------------- BN apply + SiLU -> bf16 ----------------
__global__ __launch_bounds__(256) void bnsilu_kernel(const float* __restrict__ in,
                                                     const float* __restrict__ meanp,
                                                     const float* __restrict__ rstdp,
                                                     const float* __restrict__ g,
                                                     const float* __restrict__ bb,
                                                     ushort_t* __restrict__ outp)
{
    const size_t idx = ((size_t)blockIdx.x * 256 + threadIdx.x) * 4;
    const int d = (int)(idx & (Dn - 1));
    const float4 v = *(const float4*)(in + idx);
    ushort4 r;
    {
        float t;
        t = (v.x - meanp[d + 0]) * rstdp[d + 0] * g[d + 0] + bb[d + 0]; r.x = f2bfu(t * sigmoidf_(t));
        t = (v.y - meanp[d + 1]) * rstdp[d + 1] * g[d + 1] + bb[d + 1]; r.y = f2bfu(t * sigmoidf_(t));
        t = (v.z - meanp[d + 2]) * rstdp[d + 2] * g[d + 2] + bb[d + 2]; r.z = f2bfu(t * sigmoidf_(t));
        t = (v.w - meanp[d + 3]) * rstdp[d + 3] * g[d + 3] + bb[d + 3]; r.w = f2bfu(t * sigmoidf_(t));
    }
    *(ushort4*)(outp + idx) = r;
}

// ---------------- launch ----------------
extern "C" void kernel_launch(void* const* d_in, const int* in_sizes, int n_in,
                              void* d_out, int out_size, void* d_ws, size_t ws_size,
                              hipStream_t stream)
{
    const float* x         = (const float*)d_in[0];
    const float* ff1_ln_g  = (const float*)d_in[1];
    const float* ff1_ln_b  = (const float*)d_in[2];
    const float* ff1_w1    = (const float*)d_in[3];
    const float* ff1_b1    = (const float*)d_in[4];
    const float* ff1_w2    = (const float*)d_in[5];
    const float* ff1_b2    = (const float*)d_in[6];
    const float* mhsa_ln_g = (const float*)d_in[7];
    const float* mhsa_ln_b = (const float*)d_in[8];
    const float* qkv_w     = (const float*)d_in[9];
    const float* qkv_b     = (const float*)d_in[10];
    const float* out_w     = (const float*)d_in[11];
    const float* out_b     = (const float*)d_in[12];
    const float* conv_ln_g = (const float*)d_in[13];
    const float* conv_ln_b = (const float*)d_in[14];
    const float* pw1_w     = (const float*)d_in[15];
    const float* pw1_b     = (const float*)d_in[16];
    const float* dw_w      = (const float*)d_in[17];
    const float* dw_b      = (const float*)d_in[18];
    const float* bn_g      = (const float*)d_in[19];
    const float* bn_b      = (const float*)d_in[20];
    const float* pw2_w     = (const float*)d_in[21];
    const float* pw2_b     = (const float*)d_in[22];
    const float* ff2_ln_g  = (const float*)d_in[23];
    const float* ff2_ln_b  = (const float*)d_in[24];
    const float* ff2_w1    = (const float*)d_in[25];
    const float* ff2_b1    = (const float*)d_in[26];
    const float* ff2_w2    = (const float*)d_in[27];
    const float* ff2_b2    = (const float*)d_in[28];
    const float* fin_ln_g  = (const float*)d_in[29];
    const float* fin_ln_b  = (const float*)d_in[30];

    char* W = (char*)d_ws;
    const size_t MB = 1u << 20;
    float*    R     = (float*)W;                   // [0,8MB)  residual f32 [8192,256]
    ushort_t* NbBF  = (ushort_t*)(W + 8 * MB);     // [8,12)   LN out bf16 [8192,256]
    ushort_t* HBF   = (ushort_t*)(W + 12 * MB);    // [12,24)  hidden bf16 (qkv [8192,768] max)
    float*    Hf32  = (float*)(W + 12 * MB);       // [12,28)  pw1 out f32 [8192,512] (conv phase only)
    float*    Cb    = (float*)(W + 12 * MB);       // [12,20)  conv out f32 (after Hf32 dead)
    ushort_t* AtBF  = (ushort_t*)(W + 24 * MB);    // [24,28)  attn out / bnsilu out bf16
    float*    part  = (float*)(W + 28 * MB);       // BN partials [256][512]
    float*    meanp = part + 131072;
    float*    rstdp = meanp + 256;
    ushort_t* wbuf  = (ushort_t*)(W + 29 * MB);    // bf16 transposed weights (~1.92 MB)

    ushort_t* qkvT = wbuf;
    ushort_t* outT = wbuf + 196608;
    ushort_t* f11T = wbuf + 262144;
    ushort_t* f12T = wbuf + 393216;
    ushort_t* f21T = wbuf + 524288;
    ushort_t* f22T = wbuf + 655360;
    ushort_t* pw1T = wbuf + 786432;
    ushort_t* pw2T = wbuf + 917504;

    const dim3 blk(256);

    // ---- weight prep (once per launch; graph-capture safe) ----
    WP wp;
    wp.s[0] = qkv_w;  wp.off[0] = 0;      wp.Kd[0] = 256; wp.Nd[0] = 768;
    wp.s[1] = out_w;  wp.off[1] = 196608; wp.Kd[1] = 256; wp.Nd[1] = 256;
    wp.s[2] = ff1_w1; wp.off[2] = 262144; wp.Kd[2] = 256; wp.Nd[2] = 512;
    wp.s[3] = ff1_w2; wp.off[3] = 393216; wp.Kd[3] = 512; wp.Nd[3] = 256;
    wp.s[4] = ff2_w1; wp.off[4] = 524288; wp.Kd[4] = 256; wp.Nd[4] = 512;
    wp.s[5] = ff2_w2; wp.off[5] = 655360; wp.Kd[5] = 512; wp.Nd[5] = 256;
    wp.s[6] = pw1_w;  wp.off[6] = 786432; wp.Kd[6] = 256; wp.Nd[6] = 512;
    wp.s[7] = pw2_w;  wp.off[7] = 917504; wp.Kd[7] = 256; wp.Nd[7] = 256;
    wprep_kernel<<<dim3(12, 16, 8), blk, 0, stream>>>(wp, wbuf);

    // ---- FF1 ----
    ln_kernel<1><<<NTOK / 4, blk, 0, stream>>>(x, ff1_ln_g, ff1_ln_b, NbBF);
    bgemm_kernel<1><<<dim3(64, 4), blk, 0, stream>>>(NbBF, f11T, ff1_b1, nullptr, HBF, 512, 256, 0.f);
    bgemm_kernel<2><<<dim3(64, 2), blk, 0, stream>>>(HBF, f12T, ff1_b2, x, R, 256, 512, 0.5f);

    // ---- MHSA ----
    ln_kernel<1><<<NTOK / 4, blk, 0, stream>>>(R, mhsa_ln_g, mhsa_ln_b, NbBF);
    bgemm_kernel<0><<<dim3(64, 6), blk, 0, stream>>>(NbBF, qkvT, qkv_b, nullptr, HBF, 768, 256, 0.f);
    attn_mfma_kernel<<<dim3(16, 32), blk, 0, stream>>>(HBF, AtBF);
    bgemm_kernel<2><<<dim3(64, 2), blk, 0, stream>>>(AtBF, outT, out_b, R, R, 256, 256, 1.f);

    // ---- Conv module ----
    ln_kernel<1><<<NTOK / 4, blk, 0, stream>>>(R, conv_ln_g, conv_ln_b, NbBF);
    bgemm_kernel<3><<<dim3(64, 4), blk, 0, stream>>>(NbBF, pw1T, pw1_b, nullptr, Hf32, 512, 256, 0.f);
    glu_kernel<<<NTOK * Dn / 4 / 256, blk, 0, stream>>>(Hf32, (float*)d_out);
    dwconv_kernel<<<dim3(Tn / 8, Bn), blk, 0, stream>>>((float*)d_out, dw_w, dw_b, Cb);
    bnpart_kernel<<<256, blk, 0, stream>>>(Cb, part);
    bnfin_kernel<<<1, blk, 0, stream>>>(part, meanp, rstdp);
    bnsilu_kernel<<<NTOK * Dn / 4 / 256, blk, 0, stream>>>(Cb, meanp, rstdp, bn_g, bn_b, AtBF);
    bgemm_kernel<2><<<dim3(64, 2), blk, 0, stream>>>(AtBF, pw2T, pw2_b, R, R, 256, 256, 1.f);

    // ---- FF2 ----
    ln_kernel<1><<<NTOK / 4, blk, 0, stream>>>(R, ff2_ln_g, ff2_ln_b, NbBF);
    bgemm_kernel<1><<<dim3(64, 4), blk, 0, stream>>>(NbBF, f21T, ff2_b1, nullptr, HBF, 512, 256, 0.f);
    bgemm_kernel<2><<<dim3(64, 2), blk, 0, stream>>>(HBF, f22T, ff2_b2, R, R, 256, 512, 0.5f);

    // ---- Final LN (f32 out) ----
    ln_kernel<0><<<NTOK / 4, blk, 0, stream>>>(R, fin_ln_g, fin_ln_b, d_out);
}

// Round 6
// 369.487 us; speedup vs baseline: 3.6793x; 1.0631x over previous
//
#include <hip/hip_runtime.h>
#include <hip/hip_bf16.h>

// Conformer block. B=4, T=2048, D=256, H=8, HD=32, K=31.
// All matmuls: bf16 MFMA 16x16x32, fp32 accumulate. LN/BN/residual/conv: fp32.
#define Bn 4
#define Tn 2048
#define Dn 256
#define Hn 8
#define HDn 32
#define KW 31
#define EPSV 1e-5f
#define NTOK (Bn * Tn)   // 8192 tokens

typedef __attribute__((ext_vector_type(8))) short bf16x8;   // 8 bf16 = 4 VGPR (MFMA A/B frag)
typedef __attribute__((ext_vector_type(4))) float f32x4;    // MFMA C/D frag
typedef unsigned short ushort_t;

__device__ __forceinline__ float sigmoidf_(float x) { return 1.f / (1.f + __expf(-x)); }
__device__ __forceinline__ unsigned short f2bfu(float f) {
    __hip_bfloat16 h = __float2bfloat16(f);
    unsigned short u; __builtin_memcpy(&u, &h, 2); return u;
}

// ---------------- LayerNorm (f32 in): one wave per row; OUT template: 0=f32, 1=bf16 ----------------
template <int OUTBF>
__global__ __launch_bounds__(256) void ln_kernel(const float* __restrict__ x,
                                                 const float* __restrict__ g,
                                                 const float* __restrict__ b,
                                                 void* __restrict__ yp)
{
    const int row  = blockIdx.x * 4 + (threadIdx.x >> 6);
    const int lane = threadIdx.x & 63;
    const float* xr = x + (size_t)row * Dn + lane * 4;
    float4 v = *(const float4*)xr;
    float s = v.x + v.y + v.z + v.w;
#pragma unroll
    for (int o = 32; o > 0; o >>= 1) s += __shfl_xor(s, o, 64);
    const float mu = s * (1.f / Dn);
    const float dx = v.x - mu, dy = v.y - mu, dz = v.z - mu, dw = v.w - mu;
    float ss = dx * dx + dy * dy + dz * dz + dw * dw;
#pragma unroll
    for (int o = 32; o > 0; o >>= 1) ss += __shfl_xor(ss, o, 64);
    const float rstd = rsqrtf(ss * (1.f / Dn) + EPSV);
    const float4 gv = *(const float4*)(g + lane * 4);
    const float4 bv = *(const float4*)(b + lane * 4);
    float o0 = dx * rstd * gv.x + bv.x;
    float o1 = dy * rstd * gv.y + bv.y;
    float o2 = dz * rstd * gv.z + bv.z;
    float o3 = dw * rstd * gv.w + bv.w;
    if (OUTBF) {
        ushort4 o4;
        o4.x = f2bfu(o0); o4.y = f2bfu(o1); o4.z = f2bfu(o2); o4.w = f2bfu(o3);
        *(ushort4*)((ushort_t*)yp + (size_t)row * Dn + lane * 4) = o4;
    } else {
        float4 o4 = {o0, o1, o2, o3};
        *(float4*)((float*)yp + (size_t)row * Dn + lane * 4) = o4;
    }
}

// ---------------- Weight prep: [K,N] f32 -> [N,K] bf16 (8 weights, one launch) ----------------
struct WP {
    const float* s[8];
    unsigned     off[8];
    int          Kd[8];
    int          Nd[8];
};

__global__ __launch_bounds__(256) void wprep_kernel(WP p, ushort_t* __restrict__ wb)
{
    const int z = blockIdx.z;
    const int N = p.Nd[z], K = p.Kd[z];
    const int n0 = blockIdx.x * 64, k0 = blockIdx.y * 32;
    if (n0 >= N || k0 >= K) return;
    const float* src = p.s[z];
    ushort_t* dst = wb + p.off[z];
    const int nl = threadIdx.x & 63, kq = threadIdx.x >> 6;
    const int n = n0 + nl;
    const int kb = k0 + kq * 8;
    bf16x8 o;
#pragma unroll
    for (int i = 0; i < 8; ++i) o[i] = (short)f2bfu(src[(size_t)(kb + i) * N + n]);
    *(bf16x8*)(dst + (size_t)n * K + kb) = o;
}

// ============ bf16 MFMA GEMM: C[M,N] = epi(A[M,K] @ Bt[N,K]^T + bias) ============
// Tile BM x 64 x 32.  256 thr = 4 waves (2x2).  BM=128: wave-tile 64x32; BM=64: 32x32.
// LDS frag-major: block bi holds lane l's 16B frag at base+bi*1024+l*16 -> lane-linear,
// zero bank conflicts (permutation folded into global address).
// EPI: 0 = bias -> bf16 ; 1 = silu(bias) -> bf16 ; 2 = res + scale*(bias+x) -> f32 ; 3 = bias -> f32
template <int EPI, int BM>
__global__ __launch_bounds__(256) void bgemm_kernel(const ushort_t* __restrict__ A,
                                                    const ushort_t* __restrict__ Bt,
                                                    const float* __restrict__ bias,
                                                    const float* __restrict__ res,
                                                    void* __restrict__ Cp,
                                                    int N, int K, float scale)
{
    constexpr int ABLK = BM / 16;     // 16-row fragment blocks of A (8 or 4)
    constexpr int AST  = ABLK / 4;    // A frag-blocks staged per thread (2 or 1)
    constexpr int MT   = BM / 32;     // MFMA row-tiles per wave (4 or 2)
    __shared__ ushort_t Af[ABLK][64][8];
    __shared__ ushort_t Bf[4][64][8];
    const int tid = threadIdx.x;
    const int w   = tid >> 6;
    const int l   = tid & 63;
    const int g   = l >> 4;
    const int q16 = l & 15;
    const int wm  = w >> 1;
    const int wn  = w & 1;
    const int row0 = blockIdx.x * BM;
    const int col0 = blockIdx.y * 64;
    const int sbi  = tid >> 6;        // staging block index 0..3

    const ushort_t* ga[AST];
#pragma unroll
    for (int i = 0; i < AST; ++i)
        ga[i] = A + (size_t)(row0 + (sbi + 4 * i) * 16 + q16) * K + g * 8;
    const ushort_t* gb = Bt + (size_t)(col0 + sbi * 16 + q16) * K + g * 8;

    f32x4 acc[MT][2];
#pragma unroll
    for (int mt = 0; mt < MT; ++mt)
#pragma unroll
        for (int nt = 0; nt < 2; ++nt) { acc[mt][nt].x = 0.f; acc[mt][nt].y = 0.f; acc[mt][nt].z = 0.f; acc[mt][nt].w = 0.f; }

    bf16x8 sa[AST], sb;
#pragma unroll
    for (int i = 0; i < AST; ++i) sa[i] = *(const bf16x8*)ga[i];
    sb = *(const bf16x8*)gb;

    const int NKT = K >> 5;
    for (int kt = 0; kt < NKT; ++kt) {
        __syncthreads();                       // previous readers done
#pragma unroll
        for (int i = 0; i < AST; ++i) *(bf16x8*)&Af[sbi + 4 * i][l][0] = sa[i];
        *(bf16x8*)&Bf[sbi][l][0] = sb;
        if (kt + 1 < NKT) {                    // prefetch next K-tile under MFMA
            const int k = (kt + 1) * 32;
#pragma unroll
            for (int i = 0; i < AST; ++i) sa[i] = *(const bf16x8*)(ga[i] + k);
            sb = *(const bf16x8*)(gb + k);
        }
        __syncthreads();
        bf16x8 af[MT], bb[2];
#pragma unroll
        for (int mt = 0; mt < MT; ++mt) af[mt] = *(const bf16x8*)&Af[wm * MT + mt][l][0];
#pragma unroll
        for (int nt = 0; nt < 2; ++nt) bb[nt] = *(const bf16x8*)&Bf[wn * 2 + nt][l][0];
#pragma unroll
        for (int mt = 0; mt < MT; ++mt)
#pragma unroll
            for (int nt = 0; nt < 2; ++nt)
                acc[mt][nt] = __builtin_amdgcn_mfma_f32_16x16x32_bf16(af[mt], bb[nt], acc[mt][nt], 0, 0, 0);
    }

    // epilogue: C/D layout col=l&15, row=g*4+r
#pragma unroll
    for (int nt = 0; nt < 2; ++nt) {
        const int col = col0 + (wn * 2 + nt) * 16 + q16;
        const float bj = bias[col];
#pragma unroll
        for (int mt = 0; mt < MT; ++mt) {
            const int rowb = row0 + (wm * MT + mt) * 16 + g * 4;
#pragma unroll
            for (int r = 0; r < 4; ++r) {
                float v = acc[mt][nt][r] + bj;
                const size_t idx = (size_t)(rowb + r) * N + col;
                if (EPI == 1) v *= sigmoidf_(v);
                if (EPI == 0 || EPI == 1) {
                    ((ushort_t*)Cp)[idx] = f2bfu(v);
                } else if (EPI == 2) {
                    ((float*)Cp)[idx] = res[idx] + scale * v;
                } else {
                    ((float*)Cp)[idx] = v;
                }
            }
        }
    }
}

// ---------------- Attention: bf16 MFMA flash, BARRIER-FREE wave-private staging ----------------
// qkv bf16 [B,T,768], out bf16 [B,T,256]. Block = 4 independent waves; wave owns 32 q-rows
// and stages its own K/V chunk (lane l owns kv-row l) -> zero __syncthreads in the kernel.
// Next-chunk global loads issued under compute (T14); LDS RAW ordering via wave-local lgkmcnt.
__global__ __launch_bounds__(256) void attn_mfma_kernel(const ushort_t* __restrict__ qkv,
                                                        ushort_t* __restrict__ out)
{
    __shared__ ushort_t Kl[4][64][40];    // per-wave K rows (b128 writes: even 8-phase banking)
    __shared__ ushort_t Vt[4][32][72];    // per-wave V^T [d][kv], col ^= (d&24)<<1
    __shared__ ushort_t Pl[4][16][72];    // per-wave P [q][kv], col ^= (row>>2)<<4

    const int tid = threadIdx.x;
    const int w   = tid >> 6;
    const int l   = tid & 63;
    const int g   = l >> 4;
    const int q16 = l & 15;
    const int b   = blockIdx.y >> 3;
    const int h   = blockIdx.y & 7;
    const int q0  = blockIdx.x * 128 + w * 32;
    const ushort_t* base = qkv + (size_t)b * Tn * 768;

    bf16x8 qf[2];
#pragma unroll
    for (int u = 0; u < 2; ++u)
        qf[u] = *(const bf16x8*)(base + (size_t)(q0 + u * 16 + q16) * 768 + h * 32 + g * 8);

    f32x4 O[2][2];
    float mrun[2][4], lrun[2][4];
#pragma unroll
    for (int u = 0; u < 2; ++u)
#pragma unroll
        for (int t = 0; t < 2; ++t) { O[u][t].x = 0.f; O[u][t].y = 0.f; O[u][t].z = 0.f; O[u][t].w = 0.f; }
#pragma unroll
    for (int u = 0; u < 2; ++u)
#pragma unroll
        for (int r = 0; r < 4; ++r) { mrun[u][r] = 0.f; lrun[u][r] = 0.f; }

    const float cs = 0.25505392367033404f;   // (1/sqrt(32)) * log2(e)

    // per-wave staging: lane l owns kv-row (c0 + l) of this (b,h)
    const ushort_t* kvp = base + (size_t)l * 768 + 256 + h * 32;
    bf16x8 nk[4], nv[4];
#pragma unroll
    for (int j = 0; j < 4; ++j) {
        nk[j] = *(const bf16x8*)(kvp + j * 8);
        nv[j] = *(const bf16x8*)(kvp + 256 + j * 8);
    }

    for (int c0 = 0; c0 < Tn; c0 += 64) {
        // write staged chunk into this wave's private LDS (no barrier needed)
#pragma unroll
        for (int j = 0; j < 4; ++j)
            *(bf16x8*)&Kl[w][l][j * 8] = nk[j];
#pragma unroll
        for (int j = 0; j < 4; ++j) {
            const int vcol = l ^ (16 * j);            // == l ^ ((d&24)<<1) for d = j*8..j*8+7
#pragma unroll
            for (int i = 0; i < 8; ++i)
                Vt[w][j * 8 + i][vcol] = (ushort_t)nv[j][i];
        }
        if (c0 + 64 < Tn) {                           // prefetch next chunk under compute
            const ushort_t* np = kvp + (size_t)(c0 + 64) * 768;
#pragma unroll
            for (int j = 0; j < 4; ++j) {
                nk[j] = *(const bf16x8*)(np + j * 8);
                nv[j] = *(const bf16x8*)(np + 256 + j * 8);
            }
        }

        bf16x8 kb[4];
#pragma unroll
        for (int t = 0; t < 4; ++t)
            kb[t] = *(const bf16x8*)&Kl[w][t * 16 + q16][g * 8];
        bf16x8 vb[2][2];
#pragma unroll
        for (int ht = 0; ht < 2; ++ht) {
            const int d = ht * 16 + q16;
#pragma unroll
            for (int c = 0; c < 2; ++c)
                vb[ht][c] = *(const bf16x8*)&Vt[w][d][(c * 32 + g * 8) ^ ((d & 24) << 1)];
        }

#pragma unroll
        for (int u = 0; u < 2; ++u) {
            float p[4][4];
#pragma unroll
            for (int t = 0; t < 4; ++t) {
                f32x4 z = {0.f, 0.f, 0.f, 0.f};
                f32x4 s = __builtin_amdgcn_mfma_f32_16x16x32_bf16(qf[u], kb[t], z, 0, 0, 0);
#pragma unroll
                for (int r = 0; r < 4; ++r) p[t][r] = s[r] * cs;
            }
            // defer-max trigger: per-lane elementwise gap check only (no cross-lane reduce
            // in the hot path; a row max exceeds THR iff some element does).
            float wgl = p[0][0] - mrun[u][0];
#pragma unroll
            for (int t = 0; t < 4; ++t)
#pragma unroll
                for (int r = 0; r < 4; ++r) wgl = fmaxf(wgl, p[t][r] - mrun[u][r]);
            if (__builtin_expect(__any(wgl > 11.f) != 0, 0)) {
                // cold path: true per-row max reduce + rescale
                float mx[4];
#pragma unroll
                for (int r = 0; r < 4; ++r)
                    mx[r] = fmaxf(fmaxf(p[0][r], p[1][r]), fmaxf(p[2][r], p[3][r]));
#pragma unroll
                for (int o = 1; o < 16; o <<= 1)
#pragma unroll
                    for (int r = 0; r < 4; ++r) mx[r] = fmaxf(mx[r], __shfl_xor(mx[r], o, 64));
#pragma unroll
                for (int r = 0; r < 4; ++r) {
                    const float mn = fmaxf(mrun[u][r], mx[r]);
                    const float f  = exp2f(mrun[u][r] - mn);
                    lrun[u][r] *= f;
                    O[u][0][r] *= f;
                    O[u][1][r] *= f;
                    mrun[u][r] = mn;
                }
            }
#pragma unroll
            for (int t = 0; t < 4; ++t)
#pragma unroll
                for (int r = 0; r < 4; ++r) {
                    const float pe = exp2f(p[t][r] - mrun[u][r]);
                    lrun[u][r] += pe;
                    Pl[w][g * 4 + r][(t * 16 + q16) ^ (g << 4)] = f2bfu(pe);
                }
            bf16x8 pa[2];
#pragma unroll
            for (int c = 0; c < 2; ++c)
                pa[c] = *(const bf16x8*)&Pl[w][q16][(c * 32 + g * 8) ^ ((q16 >> 2) << 4)];
#pragma unroll
            for (int ht = 0; ht < 2; ++ht) {
                O[u][ht] = __builtin_amdgcn_mfma_f32_16x16x32_bf16(pa[0], vb[ht][0], O[u][ht], 0, 0, 0);
                O[u][ht] = __builtin_amdgcn_mfma_f32_16x16x32_bf16(pa[1], vb[ht][1], O[u][ht], 0, 0, 0);
            }
        }
    }

#pragma unroll
    for (int u = 0; u < 2; ++u) {
#pragma unroll
        for (int o = 1; o < 16; o <<= 1)
#pragma unroll
            for (int r = 0; r < 4; ++r) lrun[u][r] += __shfl_xor(lrun[u][r], o, 64);
#pragma unroll
        for (int r = 0; r < 4; ++r) {
            const float inv = 1.f / lrun[u][r];
            const int row = b * Tn + q0 + u * 16 + g * 4 + r;
#pragma unroll
            for (int ht = 0; ht < 2; ++ht)
                out[(size_t)row * Dn + h * 32 + ht * 16 + q16] = f2bfu(O[u][ht][r] * inv);
        }
    }
}

// ---------------- GLU: [B,T,512] f32 -> [B,T,256] f32 ----------------
__global__ __launch_bounds__(256) void glu_kernel(const float* __restrict__ h,
                                                  float* __restrict__ outp)
{
    const size_t i   = (size_t)blockIdx.x * 256 + threadIdx.x;
    const size_t row = i / (Dn / 4);
    const int    c4  = (int)(i % (Dn / 4)) * 4;
    const float* hp  = h + row * (2 * Dn);
    const float4 a = *(const float4*)(hp + c4);
    const float4 g = *(const float4*)(hp + Dn + c4);
    float4 r;
    r.x = a.x * sigmoidf_(g.x);
    r.y = a.y * sigmoidf_(g.y);
    r.z = a.z * sigmoidf_(g.z);
    r.w = a.w * sigmoidf_(g.w);
    *(float4*)(outp + row * Dn + c4) = r;
}

// ---------------- Depthwise conv over time, K=31, layout [B,T,D] f32 ----------------
__global__ __launch_bounds__(256) void dwconv_kernel(const float* __restrict__ in,
                                                     const float* __restrict__ w,
                                                     const float* __restrict__ wb,
                                                     float* __restrict__ outp)
{
    const int d  = threadIdx.x;
    const int b  = blockIdx.y;
    const int t0 = blockIdx.x * 8;
    float wr[KW];
#pragma unroll
    for (int k = 0; k < KW; ++k) wr[k] = w[d * KW + k];
    const float bias = wb[d];
    const float* bin  = in + (size_t)b * Tn * Dn + d;
    float* bout       = outp + (size_t)b * Tn * Dn + d;
    if (t0 >= (KW / 2) + 1 && t0 + 8 + KW / 2 <= Tn) {
        for (int i = 0; i < 8; ++i) {
            const int t = t0 + i;
            float s = bias;
#pragma unroll
            for (int k = 0; k < KW; ++k) s = fmaf(bin[(size_t)(t + k - KW / 2) * Dn], wr[k], s);
            bout[(size_t)t * Dn] = s;
        }
    } else {
        for (int i = 0; i < 8; ++i) {
            const int t = t0 + i;
            float s = bias;
#pragma unroll
            for (int k = 0; k < KW; ++k) {
                const int tt = t + k - KW / 2;
                if (tt >= 0 && tt < Tn) s = fmaf(bin[(size_t)tt * Dn], wr[k], s);
            }
            bout[(size_t)t * Dn] = s;
        }
    }
}

// ---------------- BatchNorm stats, 2-stage coalesced ----------------
__global__ __launch_bounds__(256) void bnpart_kernel(const float* __restrict__ in,
                                                     float* __restrict__ part)
{
    const int d  = threadIdx.x;
    const int bk = blockIdx.x;
    float s = 0.f, ss = 0.f;
    const float* p = in + (size_t)bk * 32 * Dn + d;
    for (int t = 0; t < 32; ++t) {
        const float v = p[(size_t)t * Dn];
        s += v;
        ss = fmaf(v, v, ss);
    }
    part[bk * 512 + d]       = s;
    part[bk * 512 + 256 + d] = ss;
}

__global__ __launch_bounds__(256) void bnfin_kernel(const float* __restrict__ part,
                                                    float* __restrict__ meanp,
                                                    float* __restrict__ rstdp)
{
    const int d = threadIdx.x;
    float s = 0.f, ss = 0.f;
    for (int k = 0; k < 256; ++k) {
        s  += part[k * 512 + d];
        ss += part[k * 512 + 256 + d];
    }
    const float mu  = s * (1.f / NTOK);
    const float var = ss * (1.f / NTOK) - mu * mu;
    meanp[d] = mu;
    rstdp[d] = rsqrtf(var + EPSV);
}

// ---------------- BN apply + SiLU -> bf16 ----------------
__global__ __launch_bounds__(256) void bnsilu_kernel(const float* __restrict__ in,
                                                     const float* __restrict__ meanp,
                                                     const float* __restrict__ rstdp,
                                                     const float* __restrict__ g,
                                                     const float* __restrict__ bb,
                                                     ushort_t* __restrict__ outp)
{
    const size_t idx = ((size_t)blockIdx.x * 256 + threadIdx.x) * 4;
    const int d = (int)(idx & (Dn - 1));
    const float4 v = *(const float4*)(in + idx);
    ushort4 r;
    {
        float t;
        t = (v.x - meanp[d + 0]) * rstdp[d + 0] * g[d + 0] + bb[d + 0]; r.x = f2bfu(t * sigmoidf_(t));
        t = (v.y - meanp[d + 1]) * rstdp[d + 1] * g[d + 1] + bb[d + 1]; r.y = f2bfu(t * sigmoidf_(t));
        t = (v.z - meanp[d + 2]) * rstdp[d + 2] * g[d + 2] + bb[d + 2]; r.z = f2bfu(t * sigmoidf_(t));
        t = (v.w - meanp[d + 3]) * rstdp[d + 3] * g[d + 3] + bb[d + 3]; r.w = f2bfu(t * sigmoidf_(t));
    }
    *(ushort4*)(outp + idx) = r;
}

// ---------------- launch ----------------
extern "C" void kernel_launch(void* const* d_in, const int* in_sizes, int n_in,
                              void* d_out, int out_size, void* d_ws, size_t ws_size,
                              hipStream_t stream)
{
    const float* x         = (const float*)d_in[0];
    const float* ff1_ln_g  = (const float*)d_in[1];
    const float* ff1_ln_b  = (const float*)d_in[2];
    const float* ff1_w1    = (const float*)d_in[3];
    const float* ff1_b1    = (const float*)d_in[4];
    const float* ff1_w2    = (const float*)d_in[5];
    const float* ff1_b2    = (const float*)d_in[6];
    const float* mhsa_ln_g = (const float*)d_in[7];
    const float* mhsa_ln_b = (const float*)d_in[8];
    const float* qkv_w     = (const float*)d_in[9];
    const float* qkv_b     = (const float*)d_in[10];
    const float* out_w     = (const float*)d_in[11];
    const float* out_b     = (const float*)d_in[12];
    const float* conv_ln_g = (const float*)d_in[13];
    const float* conv_ln_b = (const float*)d_in[14];
    const float* pw1_w     = (const float*)d_in[15];
    const float* pw1_b     = (const float*)d_in[16];
    const float* dw_w      = (const float*)d_in[17];
    const float* dw_b      = (const float*)d_in[18];
    const float* bn_g      = (const float*)d_in[19];
    const float* bn_b      = (const float*)d_in[20];
    const float* pw2_w     = (const float*)d_in[21];
    const float* pw2_b     = (const float*)d_in[22];
    const float* ff2_ln_g  = (const float*)d_in[23];
    const float* ff2_ln_b  = (const float*)d_in[24];
    const float* ff2_w1    = (const float*)d_in[25];
    const float* ff2_b1    = (const float*)d_in[26];
    const float* ff2_w2    = (const float*)d_in[27];
    const float* ff2_b2    = (const float*)d_in[28];
    const float* fin_ln_g  = (const float*)d_in[29];
    const float* fin_ln_b  = (const float*)d_in[30];

    char* W = (char*)d_ws;
    const size_t MB = 1u << 20;
    float*    R     = (float*)W;                   // [0,8MB)  residual f32 [8192,256]
    ushort_t* NbBF  = (ushort_t*)(W + 8 * MB);     // [8,12)   LN out bf16 [8192,256]
    ushort_t* HBF   = (ushort_t*)(W + 12 * MB);    // [12,24)  hidden bf16 (qkv [8192,768] max)
    float*    Hf32  = (float*)(W + 12 * MB);       // [12,28)  pw1 out f32 [8192,512] (conv phase only)
    float*    Cb    = (float*)(W + 12 * MB);       // [12,20)  conv out f32 (after Hf32 dead)
    ushort_t* AtBF  = (ushort_t*)(W + 24 * MB);    // [24,28)  attn out / bnsilu out bf16
    float*    part  = (float*)(W + 28 * MB);       // BN partials [256][512]
    float*    meanp = part + 131072;
    float*    rstdp = meanp + 256;
    ushort_t* wbuf  = (ushort_t*)(W + 29 * MB);    // bf16 transposed weights (~1.92 MB)

    ushort_t* qkvT = wbuf;
    ushort_t* outT = wbuf + 196608;
    ushort_t* f11T = wbuf + 262144;
    ushort_t* f12T = wbuf + 393216;
    ushort_t* f21T = wbuf + 524288;
    ushort_t* f22T = wbuf + 655360;
    ushort_t* pw1T = wbuf + 786432;
    ushort_t* pw2T = wbuf + 917504;

    const dim3 blk(256);

    // ---- weight prep (once per launch; graph-capture safe) ----
    WP wp;
    wp.s[0] = qkv_w;  wp.off[0] = 0;      wp.Kd[0] = 256; wp.Nd[0] = 768;
    wp.s[1] = out_w;  wp.off[1] = 196608; wp.Kd[1] = 256; wp.Nd[1] = 256;
    wp.s[2] = ff1_w1; wp.off[2] = 262144; wp.Kd[2] = 256; wp.Nd[2] = 512;
    wp.s[3] = ff1_w2; wp.off[3] = 393216; wp.Kd[3] = 512; wp.Nd[3] = 256;
    wp.s[4] = ff2_w1; wp.off[4] = 524288; wp.Kd[4] = 256; wp.Nd[4] = 512;
    wp.s[5] = ff2_w2; wp.off[5] = 655360; wp.Kd[5] = 512; wp.Nd[5] = 256;
    wp.s[6] = pw1_w;  wp.off[6] = 786432; wp.Kd[6] = 256; wp.Nd[6] = 512;
    wp.s[7] = pw2_w;  wp.off[7] = 917504; wp.Kd[7] = 256; wp.Nd[7] = 256;
    wprep_kernel<<<dim3(12, 16, 8), blk, 0, stream>>>(wp, wbuf);

    // ---- FF1 ----
    ln_kernel<1><<<NTOK / 4, blk, 0, stream>>>(x, ff1_ln_g, ff1_ln_b, NbBF);
    bgemm_kernel<1, 128><<<dim3(64, 8), blk, 0, stream>>>(NbBF, f11T, ff1_b1, nullptr, HBF, 512, 256, 0.f);
    bgemm_kernel<2, 64><<<dim3(128, 4), blk, 0, stream>>>(HBF, f12T, ff1_b2, x, R, 256, 512, 0.5f);

    // ---- MHSA ----
    ln_kernel<1><<<NTOK / 4, blk, 0, stream>>>(R, mhsa_ln_g, mhsa_ln_b, NbBF);
    bgemm_kernel<0, 128><<<dim3(64, 12), blk, 0, stream>>>(NbBF, qkvT, qkv_b, nullptr, HBF, 768, 256, 0.f);
    attn_mfma_kernel<<<dim3(16, 32), blk, 0, stream>>>(HBF, AtBF);
    bgemm_kernel<2, 64><<<dim3(128, 4), blk, 0, stream>>>(AtBF, outT, out_b, R, R, 256, 256, 1.f);

    // ---- Conv module ----
    ln_kernel<1><<<NTOK / 4, blk, 0, stream>>>(R, conv_ln_g, conv_ln_b, NbBF);
    bgemm_kernel<3, 128><<<dim3(64, 8), blk, 0, stream>>>(NbBF, pw1T, pw1_b, nullptr, Hf32, 512, 256, 0.f);
    glu_kernel<<<NTOK * Dn / 4 / 256, blk, 0, stream>>>(Hf32, (float*)d_out);
    dwconv_kernel<<<dim3(Tn / 8, Bn), blk, 0, stream>>>((float*)d_out, dw_w, dw_b, Cb);
    bnpart_kernel<<<256, blk, 0, stream>>>(Cb, part);
    bnfin_kernel<<<1, blk, 0, stream>>>(part, meanp, rstdp);
    bnsilu_kernel<<<NTOK * Dn / 4 / 256, blk, 0, stream>>>(Cb, meanp, rstdp, bn_g, bn_b, AtBF);
    bgemm_kernel<2, 64><<<dim3(128, 4), blk, 0, stream>>>(AtBF, pw2T, pw2_b, R, R, 256, 256, 1.f);

    // ---- FF2 ----
    ln_kernel<1><<<NTOK / 4, blk, 0, stream>>>(R, ff2_ln_g, ff2_ln_b, NbBF);
    bgemm_kernel<1, 128><<<dim3(64, 8), blk, 0, stream>>>(NbBF, f21T, ff2_b1, nullptr, HBF, 512, 256, 0.f);
    bgemm_kernel<2, 64><<<dim3(128, 4), blk, 0, stream>>>(HBF, f22T, ff2_b2, R, R, 256, 512, 0.5f);

    // ---- Final LN (f32 out) ----
    ln_kernel<0><<<NTOK / 4, blk, 0, stream>>>(R, fin_ln_g, fin_ln_b, d_out);
}

// Round 8
// 357.330 us; speedup vs baseline: 3.8045x; 1.0340x over previous
//
#include <hip/hip_runtime.h>
#include <hip/hip_bf16.h>

// Conformer block. B=4, T=2048, D=256, H=8, HD=32, K=31.
// All matmuls: bf16 MFMA 16x16x32, fp32 accumulate. LN/BN/residual/conv: fp32.
#define Bn 4
#define Tn 2048
#define Dn 256
#define Hn 8
#define HDn 32
#define KW 31
#define EPSV 1e-5f
#define NTOK (Bn * Tn)   // 8192 tokens

typedef __attribute__((ext_vector_type(8))) short bf16x8;   // 8 bf16 = 4 VGPR (MFMA A/B frag)
typedef __attribute__((ext_vector_type(4))) float f32x4;    // MFMA C/D frag
typedef unsigned short ushort_t;

__device__ __forceinline__ float sigmoidf_(float x) { return 1.f / (1.f + __expf(-x)); }
__device__ __forceinline__ unsigned short f2bfu(float f) {
    __hip_bfloat16 h = __float2bfloat16(f);
    unsigned short u; __builtin_memcpy(&u, &h, 2); return u;
}
// packed f32x2 -> bf16x2 (RNE), no builtin on gfx950 -> inline asm (lo = src0)
__device__ __forceinline__ unsigned cvtpk_bf16(float lo, float hi) {
    unsigned r;
    asm("v_cvt_pk_bf16_f32 %0, %1, %2" : "=v"(r) : "v"(lo), "v"(hi));
    return r;
}
// async global->LDS DMA, 16B/lane: LDS dest = wave-uniform base + lane*16 (frag-major!)
__device__ __forceinline__ void gload16(const void* g, void* l) {
    __builtin_amdgcn_global_load_lds((const __attribute__((address_space(1))) unsigned*)g,
                                     (__attribute__((address_space(3))) unsigned*)l, 16, 0, 0);
}

// ---------------- LayerNorm (f32 in): one wave per row; OUT template: 0=f32, 1=bf16 ----------------
template <int OUTBF>
__global__ __launch_bounds__(256) void ln_kernel(const float* __restrict__ x,
                                                 const float* __restrict__ g,
                                                 const float* __restrict__ b,
                                                 void* __restrict__ yp)
{
    const int row  = blockIdx.x * 4 + (threadIdx.x >> 6);
    const int lane = threadIdx.x & 63;
    const float* xr = x + (size_t)row * Dn + lane * 4;
    float4 v = *(const float4*)xr;
    float s = v.x + v.y + v.z + v.w;
#pragma unroll
    for (int o = 32; o > 0; o >>= 1) s += __shfl_xor(s, o, 64);
    const float mu = s * (1.f / Dn);
    const float dx = v.x - mu, dy = v.y - mu, dz = v.z - mu, dw = v.w - mu;
    float ss = dx * dx + dy * dy + dz * dz + dw * dw;
#pragma unroll
    for (int o = 32; o > 0; o >>= 1) ss += __shfl_xor(ss, o, 64);
    const float rstd = rsqrtf(ss * (1.f / Dn) + EPSV);
    const float4 gv = *(const float4*)(g + lane * 4);
    const float4 bv = *(const float4*)(b + lane * 4);
    float o0 = dx * rstd * gv.x + bv.x;
    float o1 = dy * rstd * gv.y + bv.y;
    float o2 = dz * rstd * gv.z + bv.z;
    float o3 = dw * rstd * gv.w + bv.w;
    if (OUTBF) {
        ushort4 o4;
        o4.x = f2bfu(o0); o4.y = f2bfu(o1); o4.z = f2bfu(o2); o4.w = f2bfu(o3);
        *(ushort4*)((ushort_t*)yp + (size_t)row * Dn + lane * 4) = o4;
    } else {
        float4 o4 = {o0, o1, o2, o3};
        *(float4*)((float*)yp + (size_t)row * Dn + lane * 4) = o4;
    }
}

// ---------------- Weight prep: [K,N] f32 -> [N,K] bf16 (8 weights, one launch) ----------------
struct WP {
    const float* s[8];
    unsigned     off[8];
    int          Kd[8];
    int          Nd[8];
};

__global__ __launch_bounds__(256) void wprep_kernel(WP p, ushort_t* __restrict__ wb)
{
    const int z = blockIdx.z;
    const int N = p.Nd[z], K = p.Kd[z];
    const int n0 = blockIdx.x * 64, k0 = blockIdx.y * 32;
    if (n0 >= N || k0 >= K) return;
    const float* src = p.s[z];
    ushort_t* dst = wb + p.off[z];
    const int nl = threadIdx.x & 63, kq = threadIdx.x >> 6;
    const int n = n0 + nl;
    const int kb = k0 + kq * 8;
    bf16x8 o;
#pragma unroll
    for (int i = 0; i < 8; ++i) o[i] = (short)f2bfu(src[(size_t)(kb + i) * N + n]);
    *(bf16x8*)(dst + (size_t)n * K + kb) = o;
}

// ============ bf16 MFMA GEMM: C[M,N] = epi(A[M,K] @ Bt[N,K]^T + bias) ============
// Tile BM x 64 x 64, LDS DOUBLE-BUFFERED, staged via global_load_lds (16B/lane DMA):
// frag-major LDS (frag block base + lane*16) IS the gload_lds hardware write pattern,
// so staging has no VGPR round-trip, no ds_writes, and ONE barrier per K-tile.
// 256 thr = 4 waves (2x2). BM=128: wave-tile 64x32; BM=64: 32x32.
// EPI: 0 = bias->bf16 ; 1 = silu(bias)->bf16 ; 2 = res+scale*(bias+x)->f32 ; 3 = bias->f32 ;
//      4 = GLU pair (BM=64, N=512): C[.,c]=(a+ba)*sigmoid(g+bg), a=cols c, g=cols c+256 -> f32[.,256]
template <int EPI, int BM>
__global__ __launch_bounds__(256) void bgemm_kernel(const ushort_t* __restrict__ A,
                                                    const ushort_t* __restrict__ Bt,
                                                    const float* __restrict__ bias,
                                                    const float* __restrict__ res,
                                                    void* __restrict__ Cp,
                                                    int N, int K, float scale)
{
    constexpr int ABLK = BM / 16;               // A frag blocks per kk (8 or 4)
    constexpr int NB   = (EPI == 4) ? 8 : 4;    // B frag blocks per kk
    constexpr int ASTA = ABLK * 2 / 4;          // A gload_lds per wave per tile (4 or 2)
    constexpr int ASTB = NB * 2 / 4;            // B gload_lds per wave per tile (2 or 4)
    constexpr int MT   = BM / 32;               // MFMA row-tiles per wave (4 or 2)
    __shared__ ushort_t Af[2][ABLK][2][64][8];  // [buf][ablk][kk][lane][8]
    __shared__ ushort_t Bf[2][NB][2][64][8];
    constexpr int ASTRIDE = ABLK * 2 * 64 * 8;  // ushorts per A buffer
    constexpr int BSTRIDE = NB * 2 * 64 * 8;

    const int tid = threadIdx.x;
    const int w   = tid >> 6;
    const int l   = tid & 63;
    const int g   = l >> 4;
    const int q16 = l & 15;
    const int wm  = w >> 1;
    const int wn  = w & 1;
    const int row0 = blockIdx.x * BM;
    const int col0 = blockIdx.y * 64;

    // staging assignments: global addr is per-lane (carries the frag permutation),
    // LDS dest is the wave-uniform frag-block base (HW adds lane*16).
    const ushort_t* gA[ASTA];
    ushort_t* lA[ASTA];
#pragma unroll
    for (int i = 0; i < ASTA; ++i) {
        const int fs = w * ASTA + i, ablk = fs >> 1, kk = fs & 1;
        gA[i] = A + (size_t)(row0 + ablk * 16 + q16) * K + kk * 32 + g * 8;
        lA[i] = &Af[0][ablk][kk][0][0];
    }
    const ushort_t* gB[ASTB];
    ushort_t* lB[ASTB];
#pragma unroll
    for (int i = 0; i < ASTB; ++i) {
        const int fs = w * ASTB + i, nblk = fs >> 1, kk = fs & 1;
        const int coln = (EPI == 4 && nblk >= 4) ? 256 + col0 + (nblk - 4) * 16
                                                 : col0 + nblk * 16;
        gB[i] = Bt + (size_t)(coln + q16) * K + kk * 32 + g * 8;
        lB[i] = &Bf[0][nblk][kk][0][0];
    }

    f32x4 acc[MT][2];
#pragma unroll
    for (int mt = 0; mt < MT; ++mt)
#pragma unroll
        for (int nt = 0; nt < 2; ++nt) { acc[mt][nt].x = 0.f; acc[mt][nt].y = 0.f; acc[mt][nt].z = 0.f; acc[mt][nt].w = 0.f; }
    f32x4 acc2[MT][2];
    if (EPI == 4) {
#pragma unroll
        for (int mt = 0; mt < MT; ++mt)
#pragma unroll
            for (int nt = 0; nt < 2; ++nt) { acc2[mt][nt].x = 0.f; acc2[mt][nt].y = 0.f; acc2[mt][nt].z = 0.f; acc2[mt][nt].w = 0.f; }
    }

    // prologue: stage tile 0 into buffer 0
#pragma unroll
    for (int i = 0; i < ASTA; ++i) gload16(gA[i], lA[i]);
#pragma unroll
    for (int i = 0; i < ASTB; ++i) gload16(gB[i], lB[i]);
    __syncthreads();

    const int NKT = K >> 6;
    int cur = 0;
    for (int kt = 0; kt < NKT; ++kt) {
        if (kt + 1 < NKT) {   // stage next tile into the other buffer; flies under MFMA
            const int ko = (kt + 1) * 64;
            const int ao = (cur ^ 1) * ASTRIDE, bo = (cur ^ 1) * BSTRIDE;
#pragma unroll
            for (int i = 0; i < ASTA; ++i) gload16(gA[i] + ko, lA[i] + ao);
#pragma unroll
            for (int i = 0; i < ASTB; ++i) gload16(gB[i] + ko, lB[i] + bo);
        }
        bf16x8 af[2][MT], bb[2][2];
#pragma unroll
        for (int kk = 0; kk < 2; ++kk) {
#pragma unroll
            for (int mt = 0; mt < MT; ++mt) af[kk][mt] = *(const bf16x8*)&Af[cur][wm * MT + mt][kk][l][0];
#pragma unroll
            for (int nt = 0; nt < 2; ++nt) bb[kk][nt] = *(const bf16x8*)&Bf[cur][wn * 2 + nt][kk][l][0];
        }
#pragma unroll
        for (int kk = 0; kk < 2; ++kk)
#pragma unroll
            for (int mt = 0; mt < MT; ++mt)
#pragma unroll
                for (int nt = 0; nt < 2; ++nt)
                    acc[mt][nt] = __builtin_amdgcn_mfma_f32_16x16x32_bf16(af[kk][mt], bb[kk][nt], acc[mt][nt], 0, 0, 0);
        if (EPI == 4) {
            bf16x8 bg[2][2];
#pragma unroll
            for (int kk = 0; kk < 2; ++kk)
#pragma unroll
                for (int nt = 0; nt < 2; ++nt) bg[kk][nt] = *(const bf16x8*)&Bf[cur][4 + wn * 2 + nt][kk][l][0];
#pragma unroll
            for (int kk = 0; kk < 2; ++kk)
#pragma unroll
                for (int mt = 0; mt < MT; ++mt)
#pragma unroll
                    for (int nt = 0; nt < 2; ++nt)
                        acc2[mt][nt] = __builtin_amdgcn_mfma_f32_16x16x32_bf16(af[kk][mt], bg[kk][nt], acc2[mt][nt], 0, 0, 0);
        }
        __syncthreads();    // drains this tile's gload_lds (vmcnt) + all reads (lgkmcnt)
        cur ^= 1;
    }

    // epilogue: C/D layout col=l&15, row=g*4+r
#pragma unroll
    for (int nt = 0; nt < 2; ++nt) {
        const int col = col0 + (wn * 2 + nt) * 16 + q16;
        const float bj = bias[col];
        const float bj2 = (EPI == 4) ? bias[col + 256] : 0.f;
#pragma unroll
        for (int mt = 0; mt < MT; ++mt) {
            const int rowb = row0 + (wm * MT + mt) * 16 + g * 4;
#pragma unroll
            for (int r = 0; r < 4; ++r) {
                float v = acc[mt][nt][r] + bj;
                if (EPI == 1) v *= sigmoidf_(v);
                if (EPI == 0 || EPI == 1) {
                    ((ushort_t*)Cp)[(size_t)(rowb + r) * N + col] = f2bfu(v);
                } else if (EPI == 2) {
                    const size_t idx = (size_t)(rowb + r) * N + col;
                    ((float*)Cp)[idx] = res[idx] + scale * v;
                } else if (EPI == 3) {
                    ((float*)Cp)[(size_t)(rowb + r) * N + col] = v;
                } else {  // EPI == 4: GLU pair -> f32 [*,256]
                    const float vg = acc2[mt][nt][r] + bj2;
                    ((float*)Cp)[(size_t)(rowb + r) * 256 + col] = v * sigmoidf_(vg);
                }
            }
        }
    }
}

// ---------------- Attention: swapped-QK bf16 MFMA flash, barrier-free wave-private staging ----
// qkv bf16 [B,T,768], out bf16 [B,T,256]. Block = 4 independent waves; wave owns 32 q-rows.
// S^T = mfma(K,Q): lane (g,q16) holds S[kv=t*16+g*4+r][q=q16] -> softmax state is per-lane
// SCALAR (m,l per q; m kept uniform across the 4 g-lanes via cold-path shared reduce).
// P packed to bf16 via v_cvt_pk and redistributed for the PV B-operand through a tiny
// padded LDS block (4 ds_write_b64 + 2 ds_read_b128 per u). O^T = mfma(V^T, P^T).
__global__ __launch_bounds__(256) void attn_mfma_kernel(const ushort_t* __restrict__ qkv,
                                                        ushort_t* __restrict__ out)
{
    __shared__ ushort_t Kl[4][64][40];    // per-wave K rows
    __shared__ ushort_t Vt[4][32][72];    // per-wave V^T [d][kv], col ^= (d&24)<<1
    __shared__ unsigned P2[4][16][36];    // per-wave packed P^T: [q16][t][g][j], stride 36 words

    const int tid = threadIdx.x;
    const int w   = tid >> 6;
    const int l   = tid & 63;
    const int g   = l >> 4;
    const int q16 = l & 15;
    const int b   = blockIdx.y >> 3;
    const int h   = blockIdx.y & 7;
    const int q0  = blockIdx.x * 128 + w * 32;
    const ushort_t* base = qkv + (size_t)b * Tn * 768;

    bf16x8 qf[2];
#pragma unroll
    for (int u = 0; u < 2; ++u)
        qf[u] = *(const bf16x8*)(base + (size_t)(q0 + u * 16 + q16) * 768 + h * 32 + g * 8);

    f32x4 O[2][2];
    float mrun[2], lrun[2];
#pragma unroll
    for (int u = 0; u < 2; ++u) {
#pragma unroll
        for (int t = 0; t < 2; ++t) { O[u][t].x = 0.f; O[u][t].y = 0.f; O[u][t].z = 0.f; O[u][t].w = 0.f; }
        mrun[u] = 0.f; lrun[u] = 0.f;
    }

    const float cs = 0.25505392367033404f;   // (1/sqrt(32)) * log2(e)

    // P2 addressing: write word = q16*36 + t*8 + g*2 (+j); read = q16*36 + (2c+(g>>1))*8 + (g&1)*4
    unsigned* p2w  = &P2[w][0][0];
    unsigned* p2wr = p2w + q16 * 36 + g * 2;
    const int rdo0 = q16 * 36 + (g >> 1) * 8 + (g & 1) * 4;

    // per-wave staging: lane l owns kv-row (c0 + l) of this (b,h)
    const ushort_t* kvp = base + (size_t)l * 768 + 256 + h * 32;
    bf16x8 nk[4], nv[4];
#pragma unroll
    for (int j = 0; j < 4; ++j) {
        nk[j] = *(const bf16x8*)(kvp + j * 8);
        nv[j] = *(const bf16x8*)(kvp + 256 + j * 8);
    }

    for (int c0 = 0; c0 < Tn; c0 += 64) {
        // write staged chunk into this wave's private LDS (no barrier needed)
#pragma unroll
        for (int j = 0; j < 4; ++j)
            *(bf16x8*)&Kl[w][l][j * 8] = nk[j];
#pragma unroll
        for (int j = 0; j < 4; ++j) {
            const int vcol = l ^ (16 * j);            // == l ^ ((d&24)<<1) for d = j*8..j*8+7
#pragma unroll
            for (int i = 0; i < 8; ++i)
                Vt[w][j * 8 + i][vcol] = (ushort_t)nv[j][i];
        }
        if (c0 + 64 < Tn) {                           // prefetch next chunk under compute
            const ushort_t* np = kvp + (size_t)(c0 + 64) * 768;
#pragma unroll
            for (int j = 0; j < 4; ++j) {
                nk[j] = *(const bf16x8*)(np + j * 8);
                nv[j] = *(const bf16x8*)(np + 256 + j * 8);
            }
        }

        bf16x8 kb[4];
#pragma unroll
        for (int t = 0; t < 4; ++t)
            kb[t] = *(const bf16x8*)&Kl[w][t * 16 + q16][g * 8];
        bf16x8 vb[2][2];
#pragma unroll
        for (int ht = 0; ht < 2; ++ht) {
            const int d = ht * 16 + q16;
#pragma unroll
            for (int c = 0; c < 2; ++c)
                vb[ht][c] = *(const bf16x8*)&Vt[w][d][(c * 32 + g * 8) ^ ((d & 24) << 1)];
        }

#pragma unroll
        for (int u = 0; u < 2; ++u) {
            // S^T = K Q^T : lane holds S[kv=t*16+g*4+r][q=q16], log2 domain
            float p[4][4];
#pragma unroll
            for (int t = 0; t < 4; ++t) {
                f32x4 z = {0.f, 0.f, 0.f, 0.f};
                f32x4 s = __builtin_amdgcn_mfma_f32_16x16x32_bf16(kb[t], qf[u], z, 0, 0, 0);
#pragma unroll
                for (int r = 0; r < 4; ++r) p[t][r] = s[r] * cs;
            }
            // defer-max: per-lane elementwise gap check (row max exceeds THR iff some elem does)
            float wgl = p[0][0] - mrun[u];
#pragma unroll
            for (int t = 0; t < 4; ++t)
#pragma unroll
                for (int r = 0; r < 4; ++r) wgl = fmaxf(wgl, p[t][r] - mrun[u]);
            if (__builtin_expect(__any(wgl > 11.f) != 0, 0)) {
                // cold path: reduce max across the 4 g-lanes sharing q16, rescale
                float mx = p[0][0];
#pragma unroll
                for (int t = 0; t < 4; ++t)
#pragma unroll
                    for (int r = 0; r < 4; ++r) mx = fmaxf(mx, p[t][r]);
                mx = fmaxf(mx, __shfl_xor(mx, 16, 64));
                mx = fmaxf(mx, __shfl_xor(mx, 32, 64));
                const float mn = fmaxf(mrun[u], mx);
                const float f  = exp2f(mrun[u] - mn);
                lrun[u] *= f;
#pragma unroll
                for (int ht = 0; ht < 2; ++ht)
#pragma unroll
                    for (int r = 0; r < 4; ++r) O[u][ht][r] *= f;
                mrun[u] = mn;
            }
            // P = 2^(z-m), per-lane partial row-sum (final cross-g reduce at end)
            float pe[4][4];
            float ls = 0.f;
#pragma unroll
            for (int t = 0; t < 4; ++t)
#pragma unroll
                for (int r = 0; r < 4; ++r) {
                    pe[t][r] = exp2f(p[t][r] - mrun[u]);
                    ls += pe[t][r];
                }
            lrun[u] += ls;
            // pack to bf16 pairs and stage for redistribution
#pragma unroll
            for (int t = 0; t < 4; ++t) {
                uint2 wv;
                wv.x = cvtpk_bf16(pe[t][0], pe[t][1]);
                wv.y = cvtpk_bf16(pe[t][2], pe[t][3]);
                *(uint2*)(p2wr + t * 8) = wv;
            }
            // PV B-operand: lane needs kv = c*32 + g*8 + i  ->  contiguous quad in P2
            bf16x8 pb0 = *(const bf16x8*)(p2w + rdo0);
            bf16x8 pb1 = *(const bf16x8*)(p2w + rdo0 + 16);
            // O^T += V^T P^T
#pragma unroll
            for (int ht = 0; ht < 2; ++ht) {
                O[u][ht] = __builtin_amdgcn_mfma_f32_16x16x32_bf16(vb[ht][0], pb0, O[u][ht], 0, 0, 0);
                O[u][ht] = __builtin_amdgcn_mfma_f32_16x16x32_bf16(vb[ht][1], pb1, O[u][ht], 0, 0, 0);
            }
        }
    }

    // finalize: reduce l across the 4 g-lanes of each q, normalize, contiguous bf16 store
#pragma unroll
    for (int u = 0; u < 2; ++u) {
        float lr = lrun[u];
        lr += __shfl_xor(lr, 16, 64);
        lr += __shfl_xor(lr, 32, 64);
        const float inv = 1.f / lr;
        const size_t row = (size_t)(b * Tn + q0 + u * 16 + q16);
#pragma unroll
        for (int ht = 0; ht < 2; ++ht) {
            uint2 ov;
            ov.x = cvtpk_bf16(O[u][ht][0] * inv, O[u][ht][1] * inv);
            ov.y = cvtpk_bf16(O[u][ht][2] * inv, O[u][ht][3] * inv);
            *(uint2*)(out + row * Dn + h * 32 + ht * 16 + g * 4) = ov;
        }
    }
}

// ---------------- Depthwise conv over time, K=31, layout [B,T,D] f32 ----------------
__global__ __launch_bounds__(256) void dwconv_kernel(const float* __restrict__ in,
                                                     const float* __restrict__ w,
                                                     const float* __restrict__ wb,
                                                     float* __restrict__ outp)
{
    const int d  = threadIdx.x;
    const int b  = blockIdx.y;
    const int t0 = blockIdx.x * 8;
    float wr[KW];
#pragma unroll
    for (int k = 0; k < KW; ++k) wr[k] = w[d * KW + k];
    const float bias = wb[d];
    const float* bin  = in + (size_t)b * Tn * Dn + d;
    float* bout       = outp + (size_t)b * Tn * Dn + d;
    if (t0 >= (KW / 2) + 1 && t0 + 8 + KW / 2 <= Tn) {
        for (int i = 0; i < 8; ++i) {
            const int t = t0 + i;
            float s = bias;
#pragma unroll
            for (int k = 0; k < KW; ++k) s = fmaf(bin[(size_t)(t + k - KW / 2) * Dn], wr[k], s);
            bout[(size_t)t * Dn] = s;
        }
    } else {
        for (int i = 0; i < 8; ++i) {
            const int t = t0 + i;
            float s = bias;
#pragma unroll
            for (int k = 0; k < KW; ++k) {
                const int tt = t + k - KW / 2;
                if (tt >= 0 && tt < Tn) s = fmaf(bin[(size_t)tt * Dn], wr[k], s);
            }
            bout[(size_t)t * Dn] = s;
        }
    }
}

// ---------------- BatchNorm stats, 2-stage coalesced ----------------
__global__ __launch_bounds__(256) void bnpart_kernel(const float* __restrict__ in,
                                                     float* __restrict__ part)
{
    const int d  = threadIdx.x;
    const int bk = blockIdx.x;
    float s = 0.f, ss = 0.f;
    const float* p = in + (size_t)bk * 32 * Dn + d;
    for (int t = 0; t < 32; ++t) {
        const float v = p[(size_t)t * Dn];
        s += v;
        ss = fmaf(v, v, ss);
    }
    part[bk * 512 + d]       = s;
    part[bk * 512 + 256 + d] = ss;
}

__global__ __launch_bounds__(256) void bnfin_kernel(const float* __restrict__ part,
                                                    float* __restrict__ meanp,
                                                    float* __restrict__ rstdp)
{
    const int d = threadIdx.x;
    float s = 0.f, ss = 0.f;
    for (int k = 0; k < 256; ++k) {
        s  += part[k * 512 + d];
        ss += part[k * 512 + 256 + d];
    }
    const float mu  = s * (1.f / NTOK);
    const float var = ss * (1.f / NTOK) - mu * mu;
    meanp[d] = mu;
    rstdp[d] = rsqrtf(var + EPSV);
}

// ---------------- BN apply + SiLU -> bf16 ----------------
__global__ __launch_bounds__(256) void bnsilu_kernel(const float* __restrict__ in,
                                                     const float* __restrict__ meanp,
                                                     const float* __restrict__ rstdp,
                                                     const float* __restrict__ g,
                                                     const float* __restrict__ bb,
                                                     ushort_t* __restrict__ outp)
{
    const size_t idx = ((size_t)blockIdx.x * 256 + threadIdx.x) * 4;
    const int d = (int)(idx & (Dn - 1));
    const float4 v = *(const float4*)(in + idx);
    ushort4 r;
    {
        float t;
        t = (v.x - meanp[d + 0]) * rstdp[d + 0] * g[d + 0] + bb[d + 0]; r.x = f2bfu(t * sigmoidf_(t));
        t = (v.y - meanp[d + 1]) * rstdp[d + 1] * g[d + 1] + bb[d + 1]; r.y = f2bfu(t * sigmoidf_(t));
        t = (v.z - meanp[d + 2]) * rstdp[d + 2] * g[d + 2] + bb[d + 2]; r.z = f2bfu(t * sigmoidf_(t));
        t = (v.w - meanp[d + 3]) * rstdp[d + 3] * g[d + 3] + bb[d + 3]; r.w = f2bfu(t * sigmoidf_(t));
    }
    *(ushort4*)(outp + idx) = r;
}

// ---------------- launch ----------------
extern "C" void kernel_launch(void* const* d_in, const int* in_sizes, int n_in,
                              void* d_out, int out_size, void* d_ws, size_t ws_size,
                              hipStream_t stream)
{
    const float* x         = (const float*)d_in[0];
    const float* ff1_ln_g  = (const float*)d_in[1];
    const float* ff1_ln_b  = (const float*)d_in[2];
    const float* ff1_w1    = (const float*)d_in[3];
    const float* ff1_b1    = (const float*)d_in[4];
    const float* ff1_w2    = (const float*)d_in[5];
    const float* ff1_b2    = (const float*)d_in[6];
    const float* mhsa_ln_g = (const float*)d_in[7];
    const float* mhsa_ln_b = (const float*)d_in[8];
    const float* qkv_w     = (const float*)d_in[9];
    const float* qkv_b     = (const float*)d_in[10];
    const float* out_w     = (const float*)d_in[11];
    const float* out_b     = (const float*)d_in[12];
    const float* conv_ln_g = (const float*)d_in[13];
    const float* conv_ln_b = (const float*)d_in[14];
    const float* pw1_w     = (const float*)d_in[15];
    const float* pw1_b     = (const float*)d_in[16];
    const float* dw_w      = (const float*)d_in[17];
    const float* dw_b      = (const float*)d_in[18];
    const float* bn_g      = (const float*)d_in[19];
    const float* bn_b      = (const float*)d_in[20];
    const float* pw2_w     = (const float*)d_in[21];
    const float* pw2_b     = (const float*)d_in[22];
    const float* ff2_ln_g  = (const float*)d_in[23];
    const float* ff2_ln_b  = (const float*)d_in[24];
    const float* ff2_w1    = (const float*)d_in[25];
    const float* ff2_b1    = (const float*)d_in[26];
    const float* ff2_w2    = (const float*)d_in[27];
    const float* ff2_b2    = (const float*)d_in[28];
    const float* fin_ln_g  = (const float*)d_in[29];
    const float* fin_ln_b  = (const float*)d_in[30];

    char* W = (char*)d_ws;
    const size_t MB = 1u << 20;
    float*    R     = (float*)W;                   // [0,8MB)  residual f32 [8192,256]
    ushort_t* NbBF  = (ushort_t*)(W + 8 * MB);     // [8,12)   LN out bf16 [8192,256]
    ushort_t* HBF   = (ushort_t*)(W + 12 * MB);    // [12,24)  hidden bf16 (qkv [8192,768] max)
    float*    Cb    = (float*)(W + 12 * MB);       // [12,20)  conv out f32 (conv phase only)
    ushort_t* AtBF  = (ushort_t*)(W + 24 * MB);    // [24,28)  attn out / bnsilu out bf16
    float*    part  = (float*)(W + 28 * MB);       // BN partials [256][512]
    float*    meanp = part + 131072;
    float*    rstdp = meanp + 256;
    ushort_t* wbuf  = (ushort_t*)(W + 29 * MB);    // bf16 transposed weights (~1.92 MB)

    ushort_t* qkvT = wbuf;
    ushort_t* outT = wbuf + 196608;
    ushort_t* f11T = wbuf + 262144;
    ushort_t* f12T = wbuf + 393216;
    ushort_t* f21T = wbuf + 524288;
    ushort_t* f22T = wbuf + 655360;
    ushort_t* pw1T = wbuf + 786432;
    ushort_t* pw2T = wbuf + 917504;

    const dim3 blk(256);

    // ---- weight prep (once per launch; graph-capture safe) ----
    WP wp;
    wp.s[0] = qkv_w;  wp.off[0] = 0;      wp.Kd[0] = 256; wp.Nd[0] = 768;
    wp.s[1] = out_w;  wp.off[1] = 196608; wp.Kd[1] = 256; wp.Nd[1] = 256;
    wp.s[2] = ff1_w1; wp.off[2] = 262144; wp.Kd[2] = 256; wp.Nd[2] = 512;
    wp.s[3] = ff1_w2; wp.off[3] = 393216; wp.Kd[3] = 512; wp.Nd[3] = 256;
    wp.s[4] = ff2_w1; wp.off[4] = 524288; wp.Kd[4] = 256; wp.Nd[4] = 512;
    wp.s[5] = ff2_w2; wp.off[5] = 655360; wp.Kd[5] = 512; wp.Nd[5] = 256;
    wp.s[6] = pw1_w;  wp.off[6] = 786432; wp.Kd[6] = 256; wp.Nd[6] = 512;
    wp.s[7] = pw2_w;  wp.off[7] = 917504; wp.Kd[7] = 256; wp.Nd[7] = 256;
    wprep_kernel<<<dim3(12, 16, 8), blk, 0, stream>>>(wp, wbuf);

    // ---- FF1 ----
    ln_kernel<1><<<NTOK / 4, blk, 0, stream>>>(x, ff1_ln_g, ff1_ln_b, NbBF);
    bgemm_kernel<1, 128><<<dim3(64, 8), blk, 0, stream>>>(NbBF, f11T, ff1_b1, nullptr, HBF, 512, 256, 0.f);
    bgemm_kernel<2, 64><<<dim3(128, 4), blk, 0, stream>>>(HBF, f12T, ff1_b2, x, R, 256, 512, 0.5f);

    // ---- MHSA ----
    ln_kernel<1><<<NTOK / 4, blk, 0, stream>>>(R, mhsa_ln_g, mhsa_ln_b, NbBF);
    bgemm_kernel<0, 128><<<dim3(64, 12), blk, 0, stream>>>(NbBF, qkvT, qkv_b, nullptr, HBF, 768, 256, 0.f);
    attn_mfma_kernel<<<dim3(16, 32), blk, 0, stream>>>(HBF, AtBF);
    bgemm_kernel<2, 64><<<dim3(128, 4), blk, 0, stream>>>(AtBF, outT, out_b, R, R, 256, 256, 1.f);

    // ---- Conv module ----
    ln_kernel<1><<<NTOK / 4, blk, 0, stream>>>(R, conv_ln_g, conv_ln_b, NbBF);
    bgemm_kernel<4, 64><<<dim3(128, 4), blk, 0, stream>>>(NbBF, pw1T, pw1_b, nullptr, (float*)d_out, 512, 256, 0.f);  // GLU fused
    dwconv_kernel<<<dim3(Tn / 8, Bn), blk, 0, stream>>>((float*)d_out, dw_w, dw_b, Cb);
    bnpart_kernel<<<256, blk, 0, stream>>>(Cb, part);
    bnfin_kernel<<<1, blk, 0, stream>>>(part, meanp, rstdp);
    bnsilu_kernel<<<NTOK * Dn / 4 / 256, blk, 0, stream>>>(Cb, meanp, rstdp, bn_g, bn_b, AtBF);
    bgemm_kernel<2, 64><<<dim3(128, 4), blk, 0, stream>>>(AtBF, pw2T, pw2_b, R, R, 256, 256, 1.f);

    // ---- FF2 ----
    ln_kernel<1><<<NTOK / 4, blk, 0, stream>>>(R, ff2_ln_g, ff2_ln_b, NbBF);
    bgemm_kernel<1, 128><<<dim3(64, 8), blk, 0, stream>>>(NbBF, f21T, ff2_b1, nullptr, HBF, 512, 256, 0.f);
    bgemm_kernel<2, 64><<<dim3(128, 4), blk, 0, stream>>>(HBF, f22T, ff2_b2, R, R, 256, 512, 0.5f);

    // ---- Final LN (f32 out) ----
    ln_kernel<0><<<NTOK / 4, blk, 0, stream>>>(R, fin_ln_g, fin_ln_b, d_out);
}